// Round 17
// baseline (864.165 us; speedup 1.0000x reference)
//
#include <hip/hip_runtime.h>

// LlamaAttention prefill, MI355X/gfx950.
// R17 vs R16 (single isolated change): GEMM staging depth 2 -> 3 half-tiles
// in flight (m201 steady state, vmcnt(6)). Previous depth-3 tests (R6, R12)
// were confounded with epilogue bugs (vt scatter / sincosf); this is the
// first clean test. Schedule: P0 stages A(t+1)h1, P2 B(t+2)h0,
// P3 B(t+2)h1 + A(t+2)h0; boundary vmcnt(6). Slot-reuse audited vs
// last-read barriers. Flash (KVBLK=128) and epilogues untouched = control.

namespace {

constexpr int T_SEQ  = 4096;
constexpr int HDIM   = 4096;
constexpr int NHEADS = 32;
constexpr int HEADD  = 128;

typedef unsigned short u16;
typedef short short8 __attribute__((ext_vector_type(8)));   // 8 x bf16 (4 VGPR)
typedef float f32x4 __attribute__((ext_vector_type(4)));
typedef float f32x16 __attribute__((ext_vector_type(16)));
typedef unsigned short u16x4 __attribute__((ext_vector_type(4)));
typedef unsigned uint2v __attribute__((ext_vector_type(2)));

__device__ __forceinline__ u16 f2bf(float x) {
  unsigned u = __float_as_uint(x);
  u += 0x7fffu + ((u >> 16) & 1u);   // round-to-nearest-even
  return (u16)(u >> 16);
}
__device__ __forceinline__ float b2f(u16 x) {
  return __uint_as_float(((unsigned)x) << 16);
}

// native 2^x: single v_exp_f32
__device__ __forceinline__ float fexp2(float x) {
#if __has_builtin(__builtin_amdgcn_exp2f)
  return __builtin_amdgcn_exp2f(x);
#else
  float r;
  asm("v_exp_f32 %0, %1" : "=v"(r) : "v"(x));
  return r;
#endif
}

// v_permlane32_swap_b32: new a = [a_lo | b_lo], new b = [a_hi | b_hi]
__device__ __forceinline__ void permswap(unsigned& a, unsigned& b) {
#if __has_builtin(__builtin_amdgcn_permlane32_swap)
  uint2v r = __builtin_amdgcn_permlane32_swap(a, b, false, false);
  a = r.x; b = r.y;
#else
  asm volatile("s_nop 1\n\tv_permlane32_swap_b32 %0, %1\n\ts_nop 1"
               : "+v"(a), "+v"(b));
#endif
}
__device__ __forceinline__ unsigned cvtpk(float lo, float hi) {
  unsigned r;
  asm("v_cvt_pk_bf16_f32 %0, %1, %2" : "=v"(r) : "v"(lo), "v"(hi));
  return r;
}

#define GLOAD16(gp, lp)                                              \
  __builtin_amdgcn_global_load_lds(                                  \
      (const __attribute__((address_space(1))) void*)(gp),           \
      (__attribute__((address_space(3))) void*)(lp), 16, 0, 0)

// ---------------- f32 -> bf16 convert (+ rope table in tail blocks) --------
__global__ void k_prep(const float4* __restrict__ in, u16x4* __restrict__ out,
                       int nconvblk, int n4,
                       const int* __restrict__ pos, float* __restrict__ tab) {
  if ((int)blockIdx.x < nconvblk) {
    int i = blockIdx.x * 256 + threadIdx.x;
    if (i >= n4) return;
    float4 v = in[i];
    u16x4 o;
    o.x = f2bf(v.x); o.y = f2bf(v.y); o.z = f2bf(v.z); o.w = f2bf(v.w);
    out[i] = o;
  } else {
    int idx = (blockIdx.x - nconvblk) * 256 + threadIdx.x;  // 0 .. T*64-1
    int t = idx >> 6, f = idx & 63;
    float inv = exp2f(-(float)f * 0.20762050593045951f);    // log2(10000)/64
    float ang = (float)pos[t] * inv;
    float sn, cs;
    sincosf(ang, &sn, &cs);
    tab[idx * 2] = cs;
    tab[idx * 2 + 1] = sn;
  }
}
__global__ void k_rope_table(const int* __restrict__ pos, float* __restrict__ tab) {
  int idx = blockIdx.x * 256 + threadIdx.x;
  int t = idx >> 6, f = idx & 63;
  float inv = exp2f(-(float)f * 0.20762050593045951f);
  float ang = (float)pos[t] * inv;
  float sn, cs;
  sincosf(ang, &sn, &cs);
  tab[idx * 2] = cs;
  tab[idx * 2 + 1] = sn;
}
__global__ void k_f32_to_bf16(const float4* __restrict__ in,
                              u16x4* __restrict__ out, int n4) {
  int i = blockIdx.x * 256 + threadIdx.x;
  if (i >= n4) return;
  float4 v = in[i];
  u16x4 o;
  o.x = f2bf(v.x); o.y = f2bf(v.y); o.z = f2bf(v.z); o.w = f2bf(v.w);
  out[i] = o;
}

// ---------------- W [K][N] f32 -> Wt [N][K] bf16, 64x64 tiles --------------
__device__ __forceinline__ void transpose_body(const float* __restrict__ W,
                                               u16* __restrict__ Wt) {
  __shared__ float tile[64 * 64];   // 16 KiB
  char* Lb = (char*)tile;
  int n0 = blockIdx.x * 64, k0 = blockIdx.y * 64;
  int tid = threadIdx.x;            // 256
  int tx = tid & 15, ky = tid >> 4;
#pragma unroll
  for (int i = 0; i < 4; ++i) {
    int k = ky + i * 16;
    float4 v = *(const float4*)(W + (size_t)(k0 + k) * HDIM + n0 + tx * 4);
#pragma unroll
    for (int j = 0; j < 4; ++j) {
      int n = tx * 4 + j;
      *(float*)(Lb + n * 256 + ((k * 4) ^ ((n & 7) << 4))) = ((const float*)&v)[j];
    }
  }
  __syncthreads();
  int kq = tid & 7, ny = tid >> 3;
#pragma unroll
  for (int p = 0; p < 2; ++p) {
    int n = ny + p * 32;
    int sw = (n & 7) << 4;
    float f[8];
#pragma unroll
    for (int h = 0; h < 2; ++h) {
      float4 v = *(const float4*)(Lb + n * 256 + ((kq * 32 + h * 16) ^ sw));
      f[h * 4 + 0] = v.x; f[h * 4 + 1] = v.y;
      f[h * 4 + 2] = v.z; f[h * 4 + 3] = v.w;
    }
    u16 o[8];
#pragma unroll
    for (int j = 0; j < 8; ++j) o[j] = f2bf(f[j]);
    *(short8*)(Wt + (size_t)(n0 + n) * HDIM + k0 + kq * 8) = *(short8*)o;
  }
}
__global__ void k_transpose_w(const float* __restrict__ W, u16* __restrict__ Wt) {
  transpose_body(W, Wt);
}
__global__ void k_transpose_all(const float* __restrict__ W0,
                                const float* __restrict__ W1,
                                const float* __restrict__ W2,
                                const float* __restrict__ W3,
                                u16* __restrict__ Wt) {
  const float* W = (blockIdx.z == 0) ? W0 : (blockIdx.z == 1) ? W1
                 : (blockIdx.z == 2) ? W2 : W3;
  transpose_body(W, Wt + (size_t)blockIdx.z * T_SEQ * HDIM);
}

// ---------------- GEMM epilogue helpers ------------------------------------
__device__ __forceinline__ void epi_rope(
    const f32x4 (&acc)[8][4], char* L, int tid, int lr, int lko,
    int wr, int wc, int bm, int bnl, u16* __restrict__ O,
    float* __restrict__ KEYS, bool qscale, const float* __restrict__ ropetab) {
#pragma unroll
  for (int n = 0; n < 4; ++n) {
    int lcol = wc * 64 + n * 16 + lr;
#pragma unroll
    for (int m = 0; m < 8; ++m) {
      int r0 = wr * 128 + m * 16 + lko * 4;
#pragma unroll
      for (int r = 0; r < 4; ++r) {
        int lrow = r0 + r;
        *(u16*)(L + lrow * 512 + ((lcol * 2) ^ ((lrow & 7) << 4))) =
            f2bf(acc[m][n][r]);
      }
    }
  }
  __syncthreads();
  const int hsel = tid >> 8, t2 = tid & 255;
  const int l16 = t2 & 15, rg = t2 >> 4;
  const size_t hbase = (size_t)((bnl >> 7) + hsel) * ((size_t)T_SEQ * HEADD);
#pragma unroll
  for (int ps = 0; ps < 16; ++ps) {
    int lrow = rg + ps * 16;
    short8 v = *(const short8*)(L + lrow * 512 +
                                ((hsel * 256 + l16 * 16) ^ ((lrow & 7) << 4)));
    unsigned* vw = (unsigned*)&v;
    unsigned pw[4];
#pragma unroll
    for (int w = 0; w < 4; ++w) pw[w] = __shfl_xor(vw[w], 8);
    const u16* vh = (const u16*)vw;
    const u16* ph = (const u16*)pw;
    int trow = bm + lrow;
    float cs[8], sn[8];
    const float* tb = ropetab + (size_t)trow * 128 + ((l16 & 7) << 4);
#pragma unroll
    for (int j2 = 0; j2 < 4; ++j2) {
      float4 v4 = *(const float4*)(tb + j2 * 4);
      cs[2 * j2] = v4.x;     sn[2 * j2] = v4.y;
      cs[2 * j2 + 1] = v4.z; sn[2 * j2 + 1] = v4.w;
    }
    float o8[8];
#pragma unroll
    for (int j = 0; j < 8; ++j) {
      float x = b2f(vh[j]), y = b2f(ph[j]);
      float r = (l16 < 8) ? x * cs[j] - y * sn[j] : x * cs[j] + y * sn[j];
      if (qscale) r *= 0.12751741530082662f;   // log2(e)/sqrt(128)
      o8[j] = r;
    }
    u16 ob[8];
#pragma unroll
    for (int j = 0; j < 8; ++j) ob[j] = f2bf(o8[j]);
    *(short8*)(O + hbase + (size_t)trow * HEADD + l16 * 8) = *(short8*)ob;
    if (KEYS) {
      f32x4 a, b;
      a[0] = o8[0]; a[1] = o8[1]; a[2] = o8[2]; a[3] = o8[3];
      b[0] = o8[4]; b[1] = o8[5]; b[2] = o8[6]; b[3] = o8[7];
      *(f32x4*)(KEYS + hbase + (size_t)trow * HEADD + l16 * 8) = a;
      *(f32x4*)(KEYS + hbase + (size_t)trow * HEADD + l16 * 8 + 4) = b;
    }
  }
}

__device__ __forceinline__ void epi_v(
    const f32x4 (&acc)[8][4], char* L, int lane, int wave, int lr, int lko,
    int wr, int wc, int bm, int bnl, u16* __restrict__ VT,
    float* __restrict__ VALS) {
#pragma unroll
  for (int p = 0; p < 2; ++p) {
    if (wr == p) {
#pragma unroll
      for (int n = 0; n < 4; ++n) {
        int lcol = wc * 64 + n * 16 + lr;
#pragma unroll
        for (int m = 0; m < 8; ++m) {
          int r0 = m * 16 + lko * 4;
#pragma unroll
          for (int r = 0; r < 4; ++r) {
            int lrow = r0 + r;
            *(float*)(L + lrow * 1024 + ((lcol * 4) ^ ((lrow & 7) << 4))) =
                acc[m][n][r];
          }
        }
      }
    }
    __syncthreads();
    const int hsel2 = lane >> 5, l32 = lane & 31;
    const size_t hb = (size_t)((bnl >> 7) + hsel2) * ((size_t)T_SEQ * HEADD);
#pragma unroll
    for (int jj = 0; jj < 16; ++jj) {
      int lrow = wave + jj * 8;
      float4 v = *(const float4*)(L + lrow * 1024 +
                                  ((lane * 16) ^ ((lrow & 7) << 4)));
      *(float4*)(VALS + hb + (size_t)(bm + p * 128 + lrow) * HEADD + l32 * 4) = v;
    }
    __syncthreads();
  }
#pragma unroll
  for (int n = 0; n < 4; ++n) {
    int cl = wc * 64 + n * 16 + lr;
    int sw = (cl & 7) << 4;
#pragma unroll
    for (int m = 0; m < 8; ++m) {
      int row2 = (wr * 128 + m * 16 + lko * 4) * 2;
      u16x4 pk;
      pk.x = f2bf(acc[m][n][0]); pk.y = f2bf(acc[m][n][1]);
      pk.z = f2bf(acc[m][n][2]); pk.w = f2bf(acc[m][n][3]);
      *(u16x4*)(L + cl * 512 + (row2 ^ sw)) = pk;
    }
  }
  __syncthreads();
  const int l31 = lane & 31, hi = lane >> 5;
#pragma unroll
  for (int i = 0; i < 16; ++i) {
    int cl = i * 16 + wave * 2 + hi;
    int sw = (cl & 7) << 4;
    short8 v = *(const short8*)(L + cl * 512 + ((l31 * 16) ^ sw));
    int colg = bnl + cl;
    size_t dst = (size_t)(colg >> 7) * ((size_t)HEADD * T_SEQ)
               + (size_t)(colg & 127) * T_SEQ + (size_t)bm + l31 * 8;
    *(short8*)(VT + dst) = v;
  }
}

// ---------------- 256^2 8-phase GEMM, depth-3 staging (vmcnt(6)) -----------
// MODE 1: f32 row-major; MODE 2: V; MODE 3: K; MODE 4: Q
template <int MODE>
__global__ __launch_bounds__(512, 2)
void k_gemm256(const u16* __restrict__ A, const u16* __restrict__ Bt,
               void* __restrict__ Cout, void* __restrict__ Cout2,
               const float* __restrict__ ropetab) {
  constexpr int NT = HDIM / 64;   // 64 K-tiles
  __shared__ u16 lds[65536];      // 128 KiB
  char* L = (char*)lds;
  const int tid = threadIdx.x, lane = tid & 63, wave = tid >> 6;
  const int lr = lane & 15, lko = lane >> 4;
  const int wr = wave >> 2, wc = wave & 3;     // 2M x 4N wave grid

  const int bsw = ((blockIdx.x & 7) << 5) | (blockIdx.x >> 3);
  const int bm = (bsw >> 4) * 256, bn = (bsw & 15) * 256;

  const char* Ag = (const char*)A;
  const char* Bg = (const char*)Bt;

  const int p0 = tid * 16, p1 = p0 + 8192;
  const int pr0 = p0 >> 7, pr1 = p1 >> 7;
  const int c0 = (p0 & 127) ^ ((pr0 & 7) << 4);
  const int c1 = (p1 & 127) ^ ((pr1 & 7) << 4);

#define STG(lb, G, gr, kt)                                                  \
  {                                                                         \
    GLOAD16((G) + (size_t)((gr) + pr0) * 8192 + (size_t)(kt) * 128 + c0,    \
            L + (lb) + p0);                                                 \
    GLOAD16((G) + (size_t)((gr) + pr1) * 8192 + (size_t)(kt) * 128 + c1,    \
            L + (lb) + p1);                                                 \
  }

  f32x4 acc[8][4] = {};

  // prologue: tile0 full + B1h0 + B1h1 + A1h0 in flight; drain tile0
  STG(0,                     Ag, bm,       0);
  STG(16384,                 Ag, bm + 128, 0);
  STG(65536,                 Bg, bn,       0);
  STG(65536 + 16384,         Bg, bn + 128, 0);
  STG(65536 + 32768,         Bg, bn,       1);
  STG(65536 + 32768 + 16384, Bg, bn + 128, 1);
  STG(32768,                 Ag, bm,       1);
  asm volatile("s_waitcnt vmcnt(6)" ::: "memory");
  __builtin_amdgcn_s_barrier();

  for (int t = 0; t < NT; ++t) {
    const int d = t & 1;
    const bool s1 = (t + 1 < NT), s2 = (t + 2 < NT);
    const char* Ab = L + d * 32768 + wr * 16384;
    const char* Bb = L + 65536 + d * 32768 + (wc >> 1) * 16384;
    const int brow = (wc & 1) * 64;

    short8 af[4][2], bf0[2][2], bf1[2][2];

    // ---- P0: read A m0-3 + B n0-1; stage A(t+1)h1; MFMA (m0-3,n0-1)
#pragma unroll
    for (int m = 0; m < 4; ++m)
#pragma unroll
      for (int kk = 0; kk < 2; ++kk) {
        int row = m * 16 + lr;
        af[m][kk] = *(const short8*)(Ab + row * 128 +
                                     ((kk * 64 + lko * 16) ^ ((row & 7) << 4)));
      }
#pragma unroll
    for (int n = 0; n < 2; ++n)
#pragma unroll
      for (int kk = 0; kk < 2; ++kk) {
        int row = brow + n * 16 + lr;
        bf0[n][kk] = *(const short8*)(Bb + row * 128 +
                                      ((kk * 64 + lko * 16) ^ ((row & 7) << 4)));
      }
    if (s1) STG((d ^ 1) * 32768 + 16384, Ag, bm + 128, t + 1);
    __builtin_amdgcn_s_barrier();
    __builtin_amdgcn_s_setprio(1);
#pragma unroll
    for (int m = 0; m < 4; ++m)
#pragma unroll
      for (int n = 0; n < 2; ++n)
#pragma unroll
        for (int kk = 0; kk < 2; ++kk)
          acc[m][n] = __builtin_amdgcn_mfma_f32_16x16x32_bf16(
              af[m][kk], bf0[n][kk], acc[m][n], 0, 0, 0);
    __builtin_amdgcn_s_setprio(0);
    __builtin_amdgcn_s_barrier();

    // ---- P1: read B n2-3; MFMA (m0-3,n2-3)
#pragma unroll
    for (int n = 0; n < 2; ++n)
#pragma unroll
      for (int kk = 0; kk < 2; ++kk) {
        int row = brow + (n + 2) * 16 + lr;
        bf1[n][kk] = *(const short8*)(Bb + row * 128 +
                                      ((kk * 64 + lko * 16) ^ ((row & 7) << 4)));
      }
    __builtin_amdgcn_s_barrier();
    __builtin_amdgcn_s_setprio(1);
#pragma unroll
    for (int m = 0; m < 4; ++m)
#pragma unroll
      for (int n = 0; n < 2; ++n)
#pragma unroll
        for (int kk = 0; kk < 2; ++kk)
          acc[m][n + 2] = __builtin_amdgcn_mfma_f32_16x16x32_bf16(
              af[m][kk], bf1[n][kk], acc[m][n + 2], 0, 0, 0);
    __builtin_amdgcn_s_setprio(0);
    __builtin_amdgcn_s_barrier();

    // ---- P2: read A m4-7; stage B(t+2)h0; MFMA (m4-7,n2-3)
#pragma unroll
    for (int m = 0; m < 4; ++m)
#pragma unroll
      for (int kk = 0; kk < 2; ++kk) {
        int row = (m + 4) * 16 + lr;
        af[m][kk] = *(const short8*)(Ab + row * 128 +
                                     ((kk * 64 + lko * 16) ^ ((row & 7) << 4)));
      }
    if (s2) STG(65536 + d * 32768, Bg, bn, t + 2);
    __builtin_amdgcn_s_barrier();
    __builtin_amdgcn_s_setprio(1);
#pragma unroll
    for (int m = 0; m < 4; ++m)
#pragma unroll
      for (int n = 0; n < 2; ++n)
#pragma unroll
        for (int kk = 0; kk < 2; ++kk)
          acc[m + 4][n + 2] = __builtin_amdgcn_mfma_f32_16x16x32_bf16(
              af[m][kk], bf1[n][kk], acc[m + 4][n + 2], 0, 0, 0);
    __builtin_amdgcn_s_setprio(0);
    __builtin_amdgcn_s_barrier();

    // ---- P3: stage B(t+2)h1 + A(t+2)h0; MFMA (m4-7,n0-1); vmcnt(6)
    if (s2) {
      STG(65536 + d * 32768 + 16384, Bg, bn + 128, t + 2);
      STG(d * 32768, Ag, bm, t + 2);
    }
    __builtin_amdgcn_s_barrier();
    __builtin_amdgcn_s_setprio(1);
#pragma unroll
    for (int m = 0; m < 4; ++m)
#pragma unroll
      for (int n = 0; n < 2; ++n)
#pragma unroll
        for (int kk = 0; kk < 2; ++kk)
          acc[m + 4][n] = __builtin_amdgcn_mfma_f32_16x16x32_bf16(
              af[m][kk], bf0[n][kk], acc[m + 4][n], 0, 0, 0);
    __builtin_amdgcn_s_setprio(0);
    if (s2)      asm volatile("s_waitcnt vmcnt(6)" ::: "memory");
    else if (s1) asm volatile("s_waitcnt vmcnt(0)" ::: "memory");
    __builtin_amdgcn_s_barrier();
  }
#undef STG

  if (MODE == 1) {
    float* O = (float*)Cout;
#pragma unroll
    for (int p = 0; p < 2; ++p) {
      if (wr == p) {
#pragma unroll
        for (int n = 0; n < 4; ++n) {
          int lcol = wc * 64 + n * 16 + lr;
#pragma unroll
          for (int m = 0; m < 8; ++m) {
            int r0 = m * 16 + lko * 4;
#pragma unroll
            for (int r = 0; r < 4; ++r) {
              int lrow = r0 + r;
              *(float*)(L + lrow * 1024 + ((lcol * 4) ^ ((lrow & 7) << 4))) =
                  acc[m][n][r];
            }
          }
        }
      }
      __syncthreads();
#pragma unroll
      for (int jj = 0; jj < 16; ++jj) {
        int lrow = wave + jj * 8;
        float4 v = *(const float4*)(L + lrow * 1024 +
                                    ((lane * 16) ^ ((lrow & 7) << 4)));
        *(float4*)(O + (size_t)(bm + p * 128 + lrow) * HDIM + bn + lane * 4) = v;
      }
      __syncthreads();
    }
  } else if (MODE == 2) {
    epi_v(acc, L, lane, wave, lr, lko, wr, wc, bm, bn,
          (u16*)Cout, (float*)Cout2);
  } else if (MODE == 3) {
    epi_rope(acc, L, tid, lr, lko, wr, wc, bm, bn,
             (u16*)Cout, (float*)Cout2, false, ropetab);
  } else {
    epi_rope(acc, L, tid, lr, lko, wr, wc, bm, bn,
             (u16*)Cout, nullptr, true, ropetab);
  }
}

// ---------------- flash attention, 8-wave 32x32, KVBLK=128 (R16) -----------
__global__ __launch_bounds__(512, 2)
void k_flash3(const u16* __restrict__ Q, const u16* __restrict__ K,
              const u16* __restrict__ Vt, u16* __restrict__ Oattn) {
  constexpr int NTI = T_SEQ / 128;   // 32 tiles
  __shared__ u16 Ks[2][128 * 128];   // 2 x 32 KiB
  __shared__ u16 Vs[2][128 * 128];   // 2 x 32 KiB
  const int tid = threadIdx.x, lane = tid & 63, wave = tid >> 6;
  const int l31 = lane & 31, hi = lane >> 5;
  const int head = blockIdx.x >> 4, qb = blockIdx.x & 15;
  const int q0 = qb * 256 + wave * 32;
  const size_t hoff = (size_t)head * T_SEQ * HEADD;
  const char* Kg = (const char*)(K + hoff);
  const char* Vg = (const char*)(Vt + hoff);
  char* KsB = (char*)Ks;
  char* VsB = (char*)Vs;

  short8 qf[8];
#pragma unroll
  for (int ks = 0; ks < 8; ++ks)
    qf[ks] = *(const short8*)(Q + hoff + (size_t)(q0 + l31) * HEADD + ks * 16 + hi * 8);

  f32x16 o[4] = {};
  float mrun = -1e30f, lrun = 0.f;

  int kc[4], vc[4];
  size_t ksrc_row[4], vsrc_row[4];
#pragma unroll
  for (int c = 0; c < 4; ++c) {
    int p = tid * 16 + c * 8192;
    int kr = p >> 8;
    kc[c] = (p & 255) ^ ((kr & 7) << 4);
    ksrc_row[c] = (size_t)kr * 256;
    int vr = p >> 8;
    vc[c] = (p & 255) ^ ((vr & 7) << 4);
    vsrc_row[c] = (size_t)vr * (T_SEQ * 2);
  }

#define STAGE(buf, jt)                                                     \
  {                                                                        \
    _Pragma("unroll")                                                      \
    for (int c = 0; c < 4; ++c) {                                          \
      int p = tid * 16 + c * 8192;                                         \
      GLOAD16(Kg + (size_t)(jt) * 32768 + ksrc_row[c] + kc[c],             \
              KsB + (buf) * 32768 + p);                                    \
      GLOAD16(Vg + vsrc_row[c] + (size_t)(jt) * 256 + vc[c],               \
              VsB + (buf) * 32768 + p);                                    \
    }                                                                      \
  }

  STAGE(0, 0);
  __syncthreads();
  int cur = 0;

  for (int jt = 0; jt < NTI; ++jt) {
    if (jt + 1 < NTI) STAGE(cur ^ 1, jt + 1);
    const int cb = cur * 32768;

    f32x16 sacc[4] = {};
#pragma unroll
    for (int h2 = 0; h2 < 4; ++h2) {
      int kr = h2 * 32 + l31;
      int swz = (kr & 7) << 4;
#pragma unroll
      for (int ks = 0; ks < 8; ++ks) {
        short8 kf = *(const short8*)(KsB + cb + kr * 256 +
                                     ((ks * 32 + hi * 16) ^ swz));
        sacc[h2] = __builtin_amdgcn_mfma_f32_32x32x16_bf16(kf, qf[ks],
                                                           sacc[h2], 0, 0, 0);
      }
    }

    float t16[16];
#pragma unroll
    for (int r = 0; r < 16; ++r)
      t16[r] = fmaxf(fmaxf(sacc[0][r], sacc[1][r]),
                     fmaxf(sacc[2][r], sacc[3][r]));
#pragma unroll
    for (int s = 8; s >= 1; s >>= 1)
#pragma unroll
      for (int r = 0; r < 8; ++r)
        if (r < s) t16[r] = fmaxf(t16[r], t16[r + s]);
    float mt;
    {
      unsigned ma = __float_as_uint(t16[0]), mb = ma;
      permswap(ma, mb);
      mt = fmaxf(__uint_as_float(ma), __uint_as_float(mb));
    }

    if (__any(mt > mrun + 11.5f)) {     // 8 * log2(e)
      float mnew = fmaxf(mrun, mt);
      float rs = fexp2(mrun - mnew);
      mrun = mnew;
      lrun *= rs;
#pragma unroll
      for (int reg = 0; reg < 16; ++reg) {
        float rb = __shfl(rs, (reg & 3) + 8 * (reg >> 2) + 4 * hi);
#pragma unroll
        for (int d0 = 0; d0 < 4; ++d0) o[d0][reg] *= rb;
      }
    }

    float ps = 0.f;
#pragma unroll
    for (int h2 = 0; h2 < 4; ++h2)
#pragma unroll
      for (int r = 0; r < 16; ++r) {
        float e = fexp2(sacc[h2][r] - mrun);
        ps += e;
        sacc[h2][r] = e;
      }
    lrun += ps;

#pragma unroll
    for (int half = 0; half < 2; ++half) {
      short8 pa[4];
#pragma unroll
      for (int h2 = 0; h2 < 2; ++h2)
#pragma unroll
        for (int kk = 0; kk < 2; ++kk) {
          const f32x16& sh = sacc[2 * half + h2];
          unsigned w[4];
#pragma unroll
          for (int m = 0; m < 2; ++m) {
            unsigned A = cvtpk(sh[8 * kk + 2 * m], sh[8 * kk + 2 * m + 1]);
            unsigned B = cvtpk(sh[8 * kk + 4 + 2 * m], sh[8 * kk + 5 + 2 * m]);
            permswap(A, B);
            w[m] = A; w[2 + m] = B;
          }
          unsigned* pw = (unsigned*)&pa[2 * h2 + kk];
          pw[0] = w[0]; pw[1] = w[1]; pw[2] = w[2]; pw[3] = w[3];
        }
#pragma unroll
      for (int d0 = 0; d0 < 4; ++d0) {
        int vr = d0 * 32 + l31;
        int swz = (vr & 7) << 4;
#pragma unroll
        for (int ks = 0; ks < 4; ++ks) {
          short8 vf = *(const short8*)(VsB + cb + vr * 256 +
                                       (((half * 4 + ks) * 32 + hi * 16) ^ swz));
          o[d0] = __builtin_amdgcn_mfma_f32_32x32x16_bf16(pa[ks], vf,
                                                          o[d0], 0, 0, 0);
        }
      }
    }
    __syncthreads();
    cur ^= 1;
  }

  float lt;
  {
    unsigned la = __float_as_uint(lrun), lb = la;
    permswap(la, lb);
    lt = __uint_as_float(la) + __uint_as_float(lb);
  }
  float rinv = 1.f / lt;
#pragma unroll
  for (int reg = 0; reg < 16; ++reg) {
    int crow = (reg & 3) + 8 * (reg >> 2) + 4 * hi;
    float rb = __shfl(rinv, crow);
    size_t trow = (size_t)(q0 + crow) * HDIM + head * 128;
#pragma unroll
    for (int d0 = 0; d0 < 4; ++d0)
      Oattn[trow + d0 * 32 + l31] = f2bf(o[d0][reg] * rb);
  }
#undef STAGE
}

}  // namespace

extern "C" void kernel_launch(void* const* d_in, const int* in_sizes, int n_in,
                              void* d_out, int out_size, void* d_ws, size_t ws_size,
                              hipStream_t stream) {
  (void)in_sizes; (void)n_in; (void)out_size;
  const float* hs  = (const float*)d_in[0];
  const int*   pos = (const int*)d_in[2];
  const float* Wq  = (const float*)d_in[3];
  const float* Wk  = (const float*)d_in[4];
  const float* Wv  = (const float*)d_in[5];
  const float* Wo  = (const float*)d_in[6];

  float* out_res  = (float*)d_out;
  float* out_keys = out_res + (size_t)T_SEQ * HDIM;
  float* out_vals = out_keys + (size_t)NHEADS * T_SEQ * HEADD;

  const size_t NEL = (size_t)T_SEQ * HDIM;   // 16.7M elems = 32 MiB bf16
  dim3 b256(256);
  dim3 b512(512);
  dim3 gemmgrid(256);

  const bool big = ws_size >= (8 * NEL * 2 + (size_t)(2 << 20));

  if (big) {
    u16* Xb  = (u16*)d_ws;
    u16* Wt4 = Xb + NEL;
    u16* qb  = Wt4 + 4 * NEL;
    u16* kb  = qb + NEL;
    u16* vt  = kb + NEL;
    float* ropetab = (float*)(vt + NEL);

    const int nconv = (int)(NEL / 4 / 256);             // 16384
    k_prep<<<dim3(nconv + T_SEQ * 64 / 256), b256, 0, stream>>>(
        (const float4*)hs, (u16x4*)Xb, nconv, (int)(NEL / 4), pos, ropetab);
    k_transpose_all<<<dim3(HDIM / 64, HDIM / 64, 4), b256, 0, stream>>>(
        Wq, Wk, Wv, Wo, Wt4);

    k_gemm256<4><<<gemmgrid, b512, 0, stream>>>(Xb, Wt4, qb, nullptr, ropetab);
    k_gemm256<3><<<gemmgrid, b512, 0, stream>>>(Xb, Wt4 + NEL, kb, out_keys,
                                                ropetab);
    k_gemm256<2><<<gemmgrid, b512, 0, stream>>>(Xb, Wt4 + 2 * NEL, vt, out_vals,
                                                nullptr);
    k_flash3<<<dim3(NHEADS * (T_SEQ / 256)), b512, 0, stream>>>(qb, kb, vt, Xb);
    k_gemm256<1><<<gemmgrid, b512, 0, stream>>>(Xb, Wt4 + 3 * NEL, d_out,
                                                nullptr, nullptr);
  } else {
    u16* Xb = (u16*)d_ws;
    u16* Wt = Xb + NEL;
    u16* qb = Wt + NEL;
    u16* kb = qb + NEL;
    u16* vt = kb + NEL;
    float* ropetab = (float*)vt;
    dim3 tw(HDIM / 64, HDIM / 64);

    k_f32_to_bf16<<<dim3((int)(NEL / 4 / 256)), b256, 0, stream>>>(
        (const float4*)hs, (u16x4*)Xb, (int)(NEL / 4));
    k_rope_table<<<dim3(T_SEQ * 64 / 256), b256, 0, stream>>>(pos, ropetab);

    k_transpose_w<<<tw, b256, 0, stream>>>(Wq, Wt);
    k_gemm256<4><<<gemmgrid, b512, 0, stream>>>(Xb, Wt, qb, nullptr, ropetab);
    k_transpose_w<<<tw, b256, 0, stream>>>(Wk, Wt);
    k_gemm256<3><<<gemmgrid, b512, 0, stream>>>(Xb, Wt, kb, out_keys, ropetab);

    k_transpose_w<<<tw, b256, 0, stream>>>(Wv, Wt);
    k_gemm256<2><<<gemmgrid, b512, 0, stream>>>(Xb, Wt, vt, out_vals, nullptr);

    k_flash3<<<dim3(NHEADS * (T_SEQ / 256)), b512, 0, stream>>>(qb, kb, vt, Xb);

    k_transpose_w<<<tw, b256, 0, stream>>>(Wo, Wt);
    k_gemm256<1><<<gemmgrid, b512, 0, stream>>>(Xb, Wt, d_out, nullptr, nullptr);
  }
}

// Round 18
// 851.623 us; speedup vs baseline: 1.0147x; 1.0147x over previous
//
#include <hip/hip_runtime.h>

// LlamaAttention prefill, MI355X/gfx950.
// R18 = exact revert to R16 (best measured: 853us). R17's clean isolated
// test showed depth-3 staging regresses (+11us) on this schedule; depth-2
// vmcnt(4) is final. Components at their structural ceilings:
//   flash3 (KVBLK=128, 8-wave 32x32 swapped-QK^T, in-reg softmax) ~306us
//   4x gemm256 (256^2, 4-phase, 3-bit swizzle, depth-2) ~110us each
//   fused rope-in-epilogue (table-based), LDS-bounce coalesced writes.

namespace {

constexpr int T_SEQ  = 4096;
constexpr int HDIM   = 4096;
constexpr int NHEADS = 32;
constexpr int HEADD  = 128;

typedef unsigned short u16;
typedef short short8 __attribute__((ext_vector_type(8)));   // 8 x bf16 (4 VGPR)
typedef float f32x4 __attribute__((ext_vector_type(4)));
typedef float f32x16 __attribute__((ext_vector_type(16)));
typedef unsigned short u16x4 __attribute__((ext_vector_type(4)));
typedef unsigned uint2v __attribute__((ext_vector_type(2)));

__device__ __forceinline__ u16 f2bf(float x) {
  unsigned u = __float_as_uint(x);
  u += 0x7fffu + ((u >> 16) & 1u);   // round-to-nearest-even
  return (u16)(u >> 16);
}
__device__ __forceinline__ float b2f(u16 x) {
  return __uint_as_float(((unsigned)x) << 16);
}

// native 2^x: single v_exp_f32
__device__ __forceinline__ float fexp2(float x) {
#if __has_builtin(__builtin_amdgcn_exp2f)
  return __builtin_amdgcn_exp2f(x);
#else
  float r;
  asm("v_exp_f32 %0, %1" : "=v"(r) : "v"(x));
  return r;
#endif
}

// v_permlane32_swap_b32: new a = [a_lo | b_lo], new b = [a_hi | b_hi]
__device__ __forceinline__ void permswap(unsigned& a, unsigned& b) {
#if __has_builtin(__builtin_amdgcn_permlane32_swap)
  uint2v r = __builtin_amdgcn_permlane32_swap(a, b, false, false);
  a = r.x; b = r.y;
#else
  asm volatile("s_nop 1\n\tv_permlane32_swap_b32 %0, %1\n\ts_nop 1"
               : "+v"(a), "+v"(b));
#endif
}
__device__ __forceinline__ unsigned cvtpk(float lo, float hi) {
  unsigned r;
  asm("v_cvt_pk_bf16_f32 %0, %1, %2" : "=v"(r) : "v"(lo), "v"(hi));
  return r;
}

#define GLOAD16(gp, lp)                                              \
  __builtin_amdgcn_global_load_lds(                                  \
      (const __attribute__((address_space(1))) void*)(gp),           \
      (__attribute__((address_space(3))) void*)(lp), 16, 0, 0)

// ---------------- f32 -> bf16 convert (+ rope table in tail blocks) --------
__global__ void k_prep(const float4* __restrict__ in, u16x4* __restrict__ out,
                       int nconvblk, int n4,
                       const int* __restrict__ pos, float* __restrict__ tab) {
  if ((int)blockIdx.x < nconvblk) {
    int i = blockIdx.x * 256 + threadIdx.x;
    if (i >= n4) return;
    float4 v = in[i];
    u16x4 o;
    o.x = f2bf(v.x); o.y = f2bf(v.y); o.z = f2bf(v.z); o.w = f2bf(v.w);
    out[i] = o;
  } else {
    int idx = (blockIdx.x - nconvblk) * 256 + threadIdx.x;  // 0 .. T*64-1
    int t = idx >> 6, f = idx & 63;
    float inv = exp2f(-(float)f * 0.20762050593045951f);    // log2(10000)/64
    float ang = (float)pos[t] * inv;
    float sn, cs;
    sincosf(ang, &sn, &cs);
    tab[idx * 2] = cs;
    tab[idx * 2 + 1] = sn;
  }
}
__global__ void k_rope_table(const int* __restrict__ pos, float* __restrict__ tab) {
  int idx = blockIdx.x * 256 + threadIdx.x;
  int t = idx >> 6, f = idx & 63;
  float inv = exp2f(-(float)f * 0.20762050593045951f);
  float ang = (float)pos[t] * inv;
  float sn, cs;
  sincosf(ang, &sn, &cs);
  tab[idx * 2] = cs;
  tab[idx * 2 + 1] = sn;
}
__global__ void k_f32_to_bf16(const float4* __restrict__ in,
                              u16x4* __restrict__ out, int n4) {
  int i = blockIdx.x * 256 + threadIdx.x;
  if (i >= n4) return;
  float4 v = in[i];
  u16x4 o;
  o.x = f2bf(v.x); o.y = f2bf(v.y); o.z = f2bf(v.z); o.w = f2bf(v.w);
  out[i] = o;
}

// ---------------- W [K][N] f32 -> Wt [N][K] bf16, 64x64 tiles --------------
__device__ __forceinline__ void transpose_body(const float* __restrict__ W,
                                               u16* __restrict__ Wt) {
  __shared__ float tile[64 * 64];   // 16 KiB
  char* Lb = (char*)tile;
  int n0 = blockIdx.x * 64, k0 = blockIdx.y * 64;
  int tid = threadIdx.x;            // 256
  int tx = tid & 15, ky = tid >> 4;
#pragma unroll
  for (int i = 0; i < 4; ++i) {
    int k = ky + i * 16;
    float4 v = *(const float4*)(W + (size_t)(k0 + k) * HDIM + n0 + tx * 4);
#pragma unroll
    for (int j = 0; j < 4; ++j) {
      int n = tx * 4 + j;
      *(float*)(Lb + n * 256 + ((k * 4) ^ ((n & 7) << 4))) = ((const float*)&v)[j];
    }
  }
  __syncthreads();
  int kq = tid & 7, ny = tid >> 3;
#pragma unroll
  for (int p = 0; p < 2; ++p) {
    int n = ny + p * 32;
    int sw = (n & 7) << 4;
    float f[8];
#pragma unroll
    for (int h = 0; h < 2; ++h) {
      float4 v = *(const float4*)(Lb + n * 256 + ((kq * 32 + h * 16) ^ sw));
      f[h * 4 + 0] = v.x; f[h * 4 + 1] = v.y;
      f[h * 4 + 2] = v.z; f[h * 4 + 3] = v.w;
    }
    u16 o[8];
#pragma unroll
    for (int j = 0; j < 8; ++j) o[j] = f2bf(f[j]);
    *(short8*)(Wt + (size_t)(n0 + n) * HDIM + k0 + kq * 8) = *(short8*)o;
  }
}
__global__ void k_transpose_w(const float* __restrict__ W, u16* __restrict__ Wt) {
  transpose_body(W, Wt);
}
__global__ void k_transpose_all(const float* __restrict__ W0,
                                const float* __restrict__ W1,
                                const float* __restrict__ W2,
                                const float* __restrict__ W3,
                                u16* __restrict__ Wt) {
  const float* W = (blockIdx.z == 0) ? W0 : (blockIdx.z == 1) ? W1
                 : (blockIdx.z == 2) ? W2 : W3;
  transpose_body(W, Wt + (size_t)blockIdx.z * T_SEQ * HDIM);
}

// ---------------- GEMM epilogue helpers ------------------------------------
__device__ __forceinline__ void epi_rope(
    const f32x4 (&acc)[8][4], char* L, int tid, int lr, int lko,
    int wr, int wc, int bm, int bnl, u16* __restrict__ O,
    float* __restrict__ KEYS, bool qscale, const float* __restrict__ ropetab) {
#pragma unroll
  for (int n = 0; n < 4; ++n) {
    int lcol = wc * 64 + n * 16 + lr;
#pragma unroll
    for (int m = 0; m < 8; ++m) {
      int r0 = wr * 128 + m * 16 + lko * 4;
#pragma unroll
      for (int r = 0; r < 4; ++r) {
        int lrow = r0 + r;
        *(u16*)(L + lrow * 512 + ((lcol * 2) ^ ((lrow & 7) << 4))) =
            f2bf(acc[m][n][r]);
      }
    }
  }
  __syncthreads();
  const int hsel = tid >> 8, t2 = tid & 255;
  const int l16 = t2 & 15, rg = t2 >> 4;
  const size_t hbase = (size_t)((bnl >> 7) + hsel) * ((size_t)T_SEQ * HEADD);
#pragma unroll
  for (int ps = 0; ps < 16; ++ps) {
    int lrow = rg + ps * 16;
    short8 v = *(const short8*)(L + lrow * 512 +
                                ((hsel * 256 + l16 * 16) ^ ((lrow & 7) << 4)));
    unsigned* vw = (unsigned*)&v;
    unsigned pw[4];
#pragma unroll
    for (int w = 0; w < 4; ++w) pw[w] = __shfl_xor(vw[w], 8);
    const u16* vh = (const u16*)vw;
    const u16* ph = (const u16*)pw;
    int trow = bm + lrow;
    float cs[8], sn[8];
    const float* tb = ropetab + (size_t)trow * 128 + ((l16 & 7) << 4);
#pragma unroll
    for (int j2 = 0; j2 < 4; ++j2) {
      float4 v4 = *(const float4*)(tb + j2 * 4);
      cs[2 * j2] = v4.x;     sn[2 * j2] = v4.y;
      cs[2 * j2 + 1] = v4.z; sn[2 * j2 + 1] = v4.w;
    }
    float o8[8];
#pragma unroll
    for (int j = 0; j < 8; ++j) {
      float x = b2f(vh[j]), y = b2f(ph[j]);
      float r = (l16 < 8) ? x * cs[j] - y * sn[j] : x * cs[j] + y * sn[j];
      if (qscale) r *= 0.12751741530082662f;   // log2(e)/sqrt(128)
      o8[j] = r;
    }
    u16 ob[8];
#pragma unroll
    for (int j = 0; j < 8; ++j) ob[j] = f2bf(o8[j]);
    *(short8*)(O + hbase + (size_t)trow * HEADD + l16 * 8) = *(short8*)ob;
    if (KEYS) {
      f32x4 a, b;
      a[0] = o8[0]; a[1] = o8[1]; a[2] = o8[2]; a[3] = o8[3];
      b[0] = o8[4]; b[1] = o8[5]; b[2] = o8[6]; b[3] = o8[7];
      *(f32x4*)(KEYS + hbase + (size_t)trow * HEADD + l16 * 8) = a;
      *(f32x4*)(KEYS + hbase + (size_t)trow * HEADD + l16 * 8 + 4) = b;
    }
  }
}

__device__ __forceinline__ void epi_v(
    const f32x4 (&acc)[8][4], char* L, int lane, int wave, int lr, int lko,
    int wr, int wc, int bm, int bnl, u16* __restrict__ VT,
    float* __restrict__ VALS) {
#pragma unroll
  for (int p = 0; p < 2; ++p) {
    if (wr == p) {
#pragma unroll
      for (int n = 0; n < 4; ++n) {
        int lcol = wc * 64 + n * 16 + lr;
#pragma unroll
        for (int m = 0; m < 8; ++m) {
          int r0 = m * 16 + lko * 4;
#pragma unroll
          for (int r = 0; r < 4; ++r) {
            int lrow = r0 + r;
            *(float*)(L + lrow * 1024 + ((lcol * 4) ^ ((lrow & 7) << 4))) =
                acc[m][n][r];
          }
        }
      }
    }
    __syncthreads();
    const int hsel2 = lane >> 5, l32 = lane & 31;
    const size_t hb = (size_t)((bnl >> 7) + hsel2) * ((size_t)T_SEQ * HEADD);
#pragma unroll
    for (int jj = 0; jj < 16; ++jj) {
      int lrow = wave + jj * 8;
      float4 v = *(const float4*)(L + lrow * 1024 +
                                  ((lane * 16) ^ ((lrow & 7) << 4)));
      *(float4*)(VALS + hb + (size_t)(bm + p * 128 + lrow) * HEADD + l32 * 4) = v;
    }
    __syncthreads();
  }
#pragma unroll
  for (int n = 0; n < 4; ++n) {
    int cl = wc * 64 + n * 16 + lr;
    int sw = (cl & 7) << 4;
#pragma unroll
    for (int m = 0; m < 8; ++m) {
      int row2 = (wr * 128 + m * 16 + lko * 4) * 2;
      u16x4 pk;
      pk.x = f2bf(acc[m][n][0]); pk.y = f2bf(acc[m][n][1]);
      pk.z = f2bf(acc[m][n][2]); pk.w = f2bf(acc[m][n][3]);
      *(u16x4*)(L + cl * 512 + (row2 ^ sw)) = pk;
    }
  }
  __syncthreads();
  const int l31 = lane & 31, hi = lane >> 5;
#pragma unroll
  for (int i = 0; i < 16; ++i) {
    int cl = i * 16 + wave * 2 + hi;
    int sw = (cl & 7) << 4;
    short8 v = *(const short8*)(L + cl * 512 + ((l31 * 16) ^ sw));
    int colg = bnl + cl;
    size_t dst = (size_t)(colg >> 7) * ((size_t)HEADD * T_SEQ)
               + (size_t)(colg & 127) * T_SEQ + (size_t)bm + l31 * 8;
    *(short8*)(VT + dst) = v;
  }
}

// ---------------- 256^2 8-phase GEMM (depth-2, vmcnt(4) — final) -----------
// MODE 1: f32 row-major; MODE 2: V; MODE 3: K; MODE 4: Q
template <int MODE>
__global__ __launch_bounds__(512, 2)
void k_gemm256(const u16* __restrict__ A, const u16* __restrict__ Bt,
               void* __restrict__ Cout, void* __restrict__ Cout2,
               const float* __restrict__ ropetab) {
  constexpr int NT = HDIM / 64;   // 64 K-tiles
  __shared__ u16 lds[65536];      // 128 KiB
  char* L = (char*)lds;
  const int tid = threadIdx.x, lane = tid & 63, wave = tid >> 6;
  const int lr = lane & 15, lko = lane >> 4;
  const int wr = wave >> 2, wc = wave & 3;     // 2M x 4N wave grid

  const int bsw = ((blockIdx.x & 7) << 5) | (blockIdx.x >> 3);
  const int bm = (bsw >> 4) * 256, bn = (bsw & 15) * 256;

  const char* Ag = (const char*)A;
  const char* Bg = (const char*)Bt;

  const int p0 = tid * 16, p1 = p0 + 8192;
  const int pr0 = p0 >> 7, pr1 = p1 >> 7;
  const int c0 = (p0 & 127) ^ ((pr0 & 7) << 4);
  const int c1 = (p1 & 127) ^ ((pr1 & 7) << 4);

#define STG(lb, G, gr, kt)                                                  \
  {                                                                         \
    GLOAD16((G) + (size_t)((gr) + pr0) * 8192 + (size_t)(kt) * 128 + c0,    \
            L + (lb) + p0);                                                 \
    GLOAD16((G) + (size_t)((gr) + pr1) * 8192 + (size_t)(kt) * 128 + c1,    \
            L + (lb) + p1);                                                 \
  }

  f32x4 acc[8][4] = {};

  STG(0,             Ag, bm,       0);
  STG(16384,         Ag, bm + 128, 0);
  STG(65536,         Bg, bn,       0);
  STG(65536 + 16384, Bg, bn + 128, 0);
  STG(65536 + 32768,         Bg, bn,       1);
  STG(65536 + 32768 + 16384, Bg, bn + 128, 1);
  asm volatile("s_waitcnt vmcnt(4)" ::: "memory");
  __builtin_amdgcn_s_barrier();

  for (int t = 0; t < NT; ++t) {
    const int d = t & 1;
    const bool sA = (t + 1 < NT), sB = (t + 2 < NT);
    const char* Ab = L + d * 32768 + wr * 16384;
    const char* Bb = L + 65536 + d * 32768 + (wc >> 1) * 16384;
    const int brow = (wc & 1) * 64;

    short8 af[4][2], bf0[2][2], bf1[2][2];

    // ---- P0
#pragma unroll
    for (int m = 0; m < 4; ++m)
#pragma unroll
      for (int kk = 0; kk < 2; ++kk) {
        int row = m * 16 + lr;
        af[m][kk] = *(const short8*)(Ab + row * 128 +
                                     ((kk * 64 + lko * 16) ^ ((row & 7) << 4)));
      }
#pragma unroll
    for (int n = 0; n < 2; ++n)
#pragma unroll
      for (int kk = 0; kk < 2; ++kk) {
        int row = brow + n * 16 + lr;
        bf0[n][kk] = *(const short8*)(Bb + row * 128 +
                                      ((kk * 64 + lko * 16) ^ ((row & 7) << 4)));
      }
    if (sA) STG((d ^ 1) * 32768, Ag, bm, t + 1);
    __builtin_amdgcn_s_barrier();
    __builtin_amdgcn_s_setprio(1);
#pragma unroll
    for (int m = 0; m < 4; ++m)
#pragma unroll
      for (int n = 0; n < 2; ++n)
#pragma unroll
        for (int kk = 0; kk < 2; ++kk)
          acc[m][n] = __builtin_amdgcn_mfma_f32_16x16x32_bf16(
              af[m][kk], bf0[n][kk], acc[m][n], 0, 0, 0);
    __builtin_amdgcn_s_setprio(0);
    __builtin_amdgcn_s_barrier();

    // ---- P1
#pragma unroll
    for (int n = 0; n < 2; ++n)
#pragma unroll
      for (int kk = 0; kk < 2; ++kk) {
        int row = brow + (n + 2) * 16 + lr;
        bf1[n][kk] = *(const short8*)(Bb + row * 128 +
                                      ((kk * 64 + lko * 16) ^ ((row & 7) << 4)));
      }
    if (sA) STG((d ^ 1) * 32768 + 16384, Ag, bm + 128, t + 1);
    __builtin_amdgcn_s_barrier();
    __builtin_amdgcn_s_setprio(1);
#pragma unroll
    for (int m = 0; m < 4; ++m)
#pragma unroll
      for (int n = 0; n < 2; ++n)
#pragma unroll
        for (int kk = 0; kk < 2; ++kk)
          acc[m][n + 2] = __builtin_amdgcn_mfma_f32_16x16x32_bf16(
              af[m][kk], bf1[n][kk], acc[m][n + 2], 0, 0, 0);
    __builtin_amdgcn_s_setprio(0);
    __builtin_amdgcn_s_barrier();

    // ---- P2
#pragma unroll
    for (int m = 0; m < 4; ++m)
#pragma unroll
      for (int kk = 0; kk < 2; ++kk) {
        int row = (m + 4) * 16 + lr;
        af[m][kk] = *(const short8*)(Ab + row * 128 +
                                     ((kk * 64 + lko * 16) ^ ((row & 7) << 4)));
      }
    if (sB) STG(65536 + d * 32768, Bg, bn, t + 2);
    __builtin_amdgcn_s_barrier();
    __builtin_amdgcn_s_setprio(1);
#pragma unroll
    for (int m = 0; m < 4; ++m)
#pragma unroll
      for (int n = 0; n < 2; ++n)
#pragma unroll
        for (int kk = 0; kk < 2; ++kk)
          acc[m + 4][n + 2] = __builtin_amdgcn_mfma_f32_16x16x32_bf16(
              af[m][kk], bf1[n][kk], acc[m + 4][n + 2], 0, 0, 0);
    __builtin_amdgcn_s_setprio(0);
    __builtin_amdgcn_s_barrier();

    // ---- P3
    if (sB) STG(65536 + d * 32768 + 16384, Bg, bn + 128, t + 2);
    __builtin_amdgcn_s_barrier();
    __builtin_amdgcn_s_setprio(1);
#pragma unroll
    for (int m = 0; m < 4; ++m)
#pragma unroll
      for (int n = 0; n < 2; ++n)
#pragma unroll
        for (int kk = 0; kk < 2; ++kk)
          acc[m + 4][n] = __builtin_amdgcn_mfma_f32_16x16x32_bf16(
              af[m][kk], bf0[n][kk], acc[m + 4][n], 0, 0, 0);
    __builtin_amdgcn_s_setprio(0);
    if (sB)      asm volatile("s_waitcnt vmcnt(4)" ::: "memory");
    else if (sA) asm volatile("s_waitcnt vmcnt(0)" ::: "memory");
    __builtin_amdgcn_s_barrier();
  }
#undef STG

  if (MODE == 1) {
    float* O = (float*)Cout;
#pragma unroll
    for (int p = 0; p < 2; ++p) {
      if (wr == p) {
#pragma unroll
        for (int n = 0; n < 4; ++n) {
          int lcol = wc * 64 + n * 16 + lr;
#pragma unroll
          for (int m = 0; m < 8; ++m) {
            int r0 = m * 16 + lko * 4;
#pragma unroll
            for (int r = 0; r < 4; ++r) {
              int lrow = r0 + r;
              *(float*)(L + lrow * 1024 + ((lcol * 4) ^ ((lrow & 7) << 4))) =
                  acc[m][n][r];
            }
          }
        }
      }
      __syncthreads();
#pragma unroll
      for (int jj = 0; jj < 16; ++jj) {
        int lrow = wave + jj * 8;
        float4 v = *(const float4*)(L + lrow * 1024 +
                                    ((lane * 16) ^ ((lrow & 7) << 4)));
        *(float4*)(O + (size_t)(bm + p * 128 + lrow) * HDIM + bn + lane * 4) = v;
      }
      __syncthreads();
    }
  } else if (MODE == 2) {
    epi_v(acc, L, lane, wave, lr, lko, wr, wc, bm, bn,
          (u16*)Cout, (float*)Cout2);
  } else if (MODE == 3) {
    epi_rope(acc, L, tid, lr, lko, wr, wc, bm, bn,
             (u16*)Cout, (float*)Cout2, false, ropetab);
  } else {
    epi_rope(acc, L, tid, lr, lko, wr, wc, bm, bn,
             (u16*)Cout, nullptr, true, ropetab);
  }
}

// ---------------- flash attention, 8-wave 32x32, KVBLK=128 (R16) -----------
__global__ __launch_bounds__(512, 2)
void k_flash3(const u16* __restrict__ Q, const u16* __restrict__ K,
              const u16* __restrict__ Vt, u16* __restrict__ Oattn) {
  constexpr int NTI = T_SEQ / 128;   // 32 tiles
  __shared__ u16 Ks[2][128 * 128];   // 2 x 32 KiB
  __shared__ u16 Vs[2][128 * 128];   // 2 x 32 KiB
  const int tid = threadIdx.x, lane = tid & 63, wave = tid >> 6;
  const int l31 = lane & 31, hi = lane >> 5;
  const int head = blockIdx.x >> 4, qb = blockIdx.x & 15;
  const int q0 = qb * 256 + wave * 32;
  const size_t hoff = (size_t)head * T_SEQ * HEADD;
  const char* Kg = (const char*)(K + hoff);
  const char* Vg = (const char*)(Vt + hoff);
  char* KsB = (char*)Ks;
  char* VsB = (char*)Vs;

  short8 qf[8];
#pragma unroll
  for (int ks = 0; ks < 8; ++ks)
    qf[ks] = *(const short8*)(Q + hoff + (size_t)(q0 + l31) * HEADD + ks * 16 + hi * 8);

  f32x16 o[4] = {};
  float mrun = -1e30f, lrun = 0.f;

  int kc[4], vc[4];
  size_t ksrc_row[4], vsrc_row[4];
#pragma unroll
  for (int c = 0; c < 4; ++c) {
    int p = tid * 16 + c * 8192;
    int kr = p >> 8;
    kc[c] = (p & 255) ^ ((kr & 7) << 4);
    ksrc_row[c] = (size_t)kr * 256;
    int vr = p >> 8;
    vc[c] = (p & 255) ^ ((vr & 7) << 4);
    vsrc_row[c] = (size_t)vr * (T_SEQ * 2);
  }

#define STAGE(buf, jt)                                                     \
  {                                                                        \
    _Pragma("unroll")                                                      \
    for (int c = 0; c < 4; ++c) {                                          \
      int p = tid * 16 + c * 8192;                                         \
      GLOAD16(Kg + (size_t)(jt) * 32768 + ksrc_row[c] + kc[c],             \
              KsB + (buf) * 32768 + p);                                    \
      GLOAD16(Vg + vsrc_row[c] + (size_t)(jt) * 256 + vc[c],               \
              VsB + (buf) * 32768 + p);                                    \
    }                                                                      \
  }

  STAGE(0, 0);
  __syncthreads();
  int cur = 0;

  for (int jt = 0; jt < NTI; ++jt) {
    if (jt + 1 < NTI) STAGE(cur ^ 1, jt + 1);
    const int cb = cur * 32768;

    f32x16 sacc[4] = {};
#pragma unroll
    for (int h2 = 0; h2 < 4; ++h2) {
      int kr = h2 * 32 + l31;
      int swz = (kr & 7) << 4;
#pragma unroll
      for (int ks = 0; ks < 8; ++ks) {
        short8 kf = *(const short8*)(KsB + cb + kr * 256 +
                                     ((ks * 32 + hi * 16) ^ swz));
        sacc[h2] = __builtin_amdgcn_mfma_f32_32x32x16_bf16(kf, qf[ks],
                                                           sacc[h2], 0, 0, 0);
      }
    }

    float t16[16];
#pragma unroll
    for (int r = 0; r < 16; ++r)
      t16[r] = fmaxf(fmaxf(sacc[0][r], sacc[1][r]),
                     fmaxf(sacc[2][r], sacc[3][r]));
#pragma unroll
    for (int s = 8; s >= 1; s >>= 1)
#pragma unroll
      for (int r = 0; r < 8; ++r)
        if (r < s) t16[r] = fmaxf(t16[r], t16[r + s]);
    float mt;
    {
      unsigned ma = __float_as_uint(t16[0]), mb = ma;
      permswap(ma, mb);
      mt = fmaxf(__uint_as_float(ma), __uint_as_float(mb));
    }

    if (__any(mt > mrun + 11.5f)) {     // 8 * log2(e)
      float mnew = fmaxf(mrun, mt);
      float rs = fexp2(mrun - mnew);
      mrun = mnew;
      lrun *= rs;
#pragma unroll
      for (int reg = 0; reg < 16; ++reg) {
        float rb = __shfl(rs, (reg & 3) + 8 * (reg >> 2) + 4 * hi);
#pragma unroll
        for (int d0 = 0; d0 < 4; ++d0) o[d0][reg] *= rb;
      }
    }

    float ps = 0.f;
#pragma unroll
    for (int h2 = 0; h2 < 4; ++h2)
#pragma unroll
      for (int r = 0; r < 16; ++r) {
        float e = fexp2(sacc[h2][r] - mrun);
        ps += e;
        sacc[h2][r] = e;
      }
    lrun += ps;

#pragma unroll
    for (int half = 0; half < 2; ++half) {
      short8 pa[4];
#pragma unroll
      for (int h2 = 0; h2 < 2; ++h2)
#pragma unroll
        for (int kk = 0; kk < 2; ++kk) {
          const f32x16& sh = sacc[2 * half + h2];
          unsigned w[4];
#pragma unroll
          for (int m = 0; m < 2; ++m) {
            unsigned A = cvtpk(sh[8 * kk + 2 * m], sh[8 * kk + 2 * m + 1]);
            unsigned B = cvtpk(sh[8 * kk + 4 + 2 * m], sh[8 * kk + 5 + 2 * m]);
            permswap(A, B);
            w[m] = A; w[2 + m] = B;
          }
          unsigned* pw = (unsigned*)&pa[2 * h2 + kk];
          pw[0] = w[0]; pw[1] = w[1]; pw[2] = w[2]; pw[3] = w[3];
        }
#pragma unroll
      for (int d0 = 0; d0 < 4; ++d0) {
        int vr = d0 * 32 + l31;
        int swz = (vr & 7) << 4;
#pragma unroll
        for (int ks = 0; ks < 4; ++ks) {
          short8 vf = *(const short8*)(VsB + cb + vr * 256 +
                                       (((half * 4 + ks) * 32 + hi * 16) ^ swz));
          o[d0] = __builtin_amdgcn_mfma_f32_32x32x16_bf16(pa[ks], vf,
                                                          o[d0], 0, 0, 0);
        }
      }
    }
    __syncthreads();
    cur ^= 1;
  }

  float lt;
  {
    unsigned la = __float_as_uint(lrun), lb = la;
    permswap(la, lb);
    lt = __uint_as_float(la) + __uint_as_float(lb);
  }
  float rinv = 1.f / lt;
#pragma unroll
  for (int reg = 0; reg < 16; ++reg) {
    int crow = (reg & 3) + 8 * (reg >> 2) + 4 * hi;
    float rb = __shfl(rinv, crow);
    size_t trow = (size_t)(q0 + crow) * HDIM + head * 128;
#pragma unroll
    for (int d0 = 0; d0 < 4; ++d0)
      Oattn[trow + d0 * 32 + l31] = f2bf(o[d0][reg] * rb);
  }
#undef STAGE
}

}  // namespace

extern "C" void kernel_launch(void* const* d_in, const int* in_sizes, int n_in,
                              void* d_out, int out_size, void* d_ws, size_t ws_size,
                              hipStream_t stream) {
  (void)in_sizes; (void)n_in; (void)out_size;
  const float* hs  = (const float*)d_in[0];
  const int*   pos = (const int*)d_in[2];
  const float* Wq  = (const float*)d_in[3];
  const float* Wk  = (const float*)d_in[4];
  const float* Wv  = (const float*)d_in[5];
  const float* Wo  = (const float*)d_in[6];

  float* out_res  = (float*)d_out;
  float* out_keys = out_res + (size_t)T_SEQ * HDIM;
  float* out_vals = out_keys + (size_t)NHEADS * T_SEQ * HEADD;

  const size_t NEL = (size_t)T_SEQ * HDIM;   // 16.7M elems = 32 MiB bf16
  dim3 b256(256);
  dim3 b512(512);
  dim3 gemmgrid(256);

  const bool big = ws_size >= (8 * NEL * 2 + (size_t)(2 << 20));

  if (big) {
    u16* Xb  = (u16*)d_ws;
    u16* Wt4 = Xb + NEL;
    u16* qb  = Wt4 + 4 * NEL;
    u16* kb  = qb + NEL;
    u16* vt  = kb + NEL;
    float* ropetab = (float*)(vt + NEL);

    const int nconv = (int)(NEL / 4 / 256);             // 16384
    k_prep<<<dim3(nconv + T_SEQ * 64 / 256), b256, 0, stream>>>(
        (const float4*)hs, (u16x4*)Xb, nconv, (int)(NEL / 4), pos, ropetab);
    k_transpose_all<<<dim3(HDIM / 64, HDIM / 64, 4), b256, 0, stream>>>(
        Wq, Wk, Wv, Wo, Wt4);

    k_gemm256<4><<<gemmgrid, b512, 0, stream>>>(Xb, Wt4, qb, nullptr, ropetab);
    k_gemm256<3><<<gemmgrid, b512, 0, stream>>>(Xb, Wt4 + NEL, kb, out_keys,
                                                ropetab);
    k_gemm256<2><<<gemmgrid, b512, 0, stream>>>(Xb, Wt4 + 2 * NEL, vt, out_vals,
                                                nullptr);
    k_flash3<<<dim3(NHEADS * (T_SEQ / 256)), b512, 0, stream>>>(qb, kb, vt, Xb);
    k_gemm256<1><<<gemmgrid, b512, 0, stream>>>(Xb, Wt4 + 3 * NEL, d_out,
                                                nullptr, nullptr);
  } else {
    u16* Xb = (u16*)d_ws;
    u16* Wt = Xb + NEL;
    u16* qb = Wt + NEL;
    u16* kb = qb + NEL;
    u16* vt = kb + NEL;
    float* ropetab = (float*)vt;
    dim3 tw(HDIM / 64, HDIM / 64);

    k_f32_to_bf16<<<dim3((int)(NEL / 4 / 256)), b256, 0, stream>>>(
        (const float4*)hs, (u16x4*)Xb, (int)(NEL / 4));
    k_rope_table<<<dim3(T_SEQ * 64 / 256), b256, 0, stream>>>(pos, ropetab);

    k_transpose_w<<<tw, b256, 0, stream>>>(Wq, Wt);
    k_gemm256<4><<<gemmgrid, b512, 0, stream>>>(Xb, Wt, qb, nullptr, ropetab);
    k_transpose_w<<<tw, b256, 0, stream>>>(Wk, Wt);
    k_gemm256<3><<<gemmgrid, b512, 0, stream>>>(Xb, Wt, kb, out_keys, ropetab);

    k_transpose_w<<<tw, b256, 0, stream>>>(Wv, Wt);
    k_gemm256<2><<<gemmgrid, b512, 0, stream>>>(Xb, Wt, vt, out_vals, nullptr);

    k_flash3<<<dim3(NHEADS * (T_SEQ / 256)), b512, 0, stream>>>(qb, kb, vt, Xb);

    k_transpose_w<<<tw, b256, 0, stream>>>(Wo, Wt);
    k_gemm256<1><<<gemmgrid, b512, 0, stream>>>(Xb, Wt, d_out, nullptr, nullptr);
  }
}

// Round 19
// 848.743 us; speedup vs baseline: 1.0182x; 1.0034x over previous
//
#include <hip/hip_runtime.h>

// LlamaAttention prefill, MI355X/gfx950.
// R19 vs R18 (single change): flash softmax row-sum `ps` split into 4
// independent accumulators. Without -ffast-math the 128 sequential
// `ps += e` adds form a real ~512-cycle dependency chain per tile
// (~= the tile's whole MFMA issue time); 4-way split cuts it to ~128.
// Static indices (unrolled) -> registers, no scratch. All else = R18.

namespace {

constexpr int T_SEQ  = 4096;
constexpr int HDIM   = 4096;
constexpr int NHEADS = 32;
constexpr int HEADD  = 128;

typedef unsigned short u16;
typedef short short8 __attribute__((ext_vector_type(8)));   // 8 x bf16 (4 VGPR)
typedef float f32x4 __attribute__((ext_vector_type(4)));
typedef float f32x16 __attribute__((ext_vector_type(16)));
typedef unsigned short u16x4 __attribute__((ext_vector_type(4)));
typedef unsigned uint2v __attribute__((ext_vector_type(2)));

__device__ __forceinline__ u16 f2bf(float x) {
  unsigned u = __float_as_uint(x);
  u += 0x7fffu + ((u >> 16) & 1u);   // round-to-nearest-even
  return (u16)(u >> 16);
}
__device__ __forceinline__ float b2f(u16 x) {
  return __uint_as_float(((unsigned)x) << 16);
}

// native 2^x: single v_exp_f32
__device__ __forceinline__ float fexp2(float x) {
#if __has_builtin(__builtin_amdgcn_exp2f)
  return __builtin_amdgcn_exp2f(x);
#else
  float r;
  asm("v_exp_f32 %0, %1" : "=v"(r) : "v"(x));
  return r;
#endif
}

// v_permlane32_swap_b32: new a = [a_lo | b_lo], new b = [a_hi | b_hi]
__device__ __forceinline__ void permswap(unsigned& a, unsigned& b) {
#if __has_builtin(__builtin_amdgcn_permlane32_swap)
  uint2v r = __builtin_amdgcn_permlane32_swap(a, b, false, false);
  a = r.x; b = r.y;
#else
  asm volatile("s_nop 1\n\tv_permlane32_swap_b32 %0, %1\n\ts_nop 1"
               : "+v"(a), "+v"(b));
#endif
}
__device__ __forceinline__ unsigned cvtpk(float lo, float hi) {
  unsigned r;
  asm("v_cvt_pk_bf16_f32 %0, %1, %2" : "=v"(r) : "v"(lo), "v"(hi));
  return r;
}

#define GLOAD16(gp, lp)                                              \
  __builtin_amdgcn_global_load_lds(                                  \
      (const __attribute__((address_space(1))) void*)(gp),           \
      (__attribute__((address_space(3))) void*)(lp), 16, 0, 0)

// ---------------- f32 -> bf16 convert (+ rope table in tail blocks) --------
__global__ void k_prep(const float4* __restrict__ in, u16x4* __restrict__ out,
                       int nconvblk, int n4,
                       const int* __restrict__ pos, float* __restrict__ tab) {
  if ((int)blockIdx.x < nconvblk) {
    int i = blockIdx.x * 256 + threadIdx.x;
    if (i >= n4) return;
    float4 v = in[i];
    u16x4 o;
    o.x = f2bf(v.x); o.y = f2bf(v.y); o.z = f2bf(v.z); o.w = f2bf(v.w);
    out[i] = o;
  } else {
    int idx = (blockIdx.x - nconvblk) * 256 + threadIdx.x;  // 0 .. T*64-1
    int t = idx >> 6, f = idx & 63;
    float inv = exp2f(-(float)f * 0.20762050593045951f);    // log2(10000)/64
    float ang = (float)pos[t] * inv;
    float sn, cs;
    sincosf(ang, &sn, &cs);
    tab[idx * 2] = cs;
    tab[idx * 2 + 1] = sn;
  }
}
__global__ void k_rope_table(const int* __restrict__ pos, float* __restrict__ tab) {
  int idx = blockIdx.x * 256 + threadIdx.x;
  int t = idx >> 6, f = idx & 63;
  float inv = exp2f(-(float)f * 0.20762050593045951f);
  float ang = (float)pos[t] * inv;
  float sn, cs;
  sincosf(ang, &sn, &cs);
  tab[idx * 2] = cs;
  tab[idx * 2 + 1] = sn;
}
__global__ void k_f32_to_bf16(const float4* __restrict__ in,
                              u16x4* __restrict__ out, int n4) {
  int i = blockIdx.x * 256 + threadIdx.x;
  if (i >= n4) return;
  float4 v = in[i];
  u16x4 o;
  o.x = f2bf(v.x); o.y = f2bf(v.y); o.z = f2bf(v.z); o.w = f2bf(v.w);
  out[i] = o;
}

// ---------------- W [K][N] f32 -> Wt [N][K] bf16, 64x64 tiles --------------
__device__ __forceinline__ void transpose_body(const float* __restrict__ W,
                                               u16* __restrict__ Wt) {
  __shared__ float tile[64 * 64];   // 16 KiB
  char* Lb = (char*)tile;
  int n0 = blockIdx.x * 64, k0 = blockIdx.y * 64;
  int tid = threadIdx.x;            // 256
  int tx = tid & 15, ky = tid >> 4;
#pragma unroll
  for (int i = 0; i < 4; ++i) {
    int k = ky + i * 16;
    float4 v = *(const float4*)(W + (size_t)(k0 + k) * HDIM + n0 + tx * 4);
#pragma unroll
    for (int j = 0; j < 4; ++j) {
      int n = tx * 4 + j;
      *(float*)(Lb + n * 256 + ((k * 4) ^ ((n & 7) << 4))) = ((const float*)&v)[j];
    }
  }
  __syncthreads();
  int kq = tid & 7, ny = tid >> 3;
#pragma unroll
  for (int p = 0; p < 2; ++p) {
    int n = ny + p * 32;
    int sw = (n & 7) << 4;
    float f[8];
#pragma unroll
    for (int h = 0; h < 2; ++h) {
      float4 v = *(const float4*)(Lb + n * 256 + ((kq * 32 + h * 16) ^ sw));
      f[h * 4 + 0] = v.x; f[h * 4 + 1] = v.y;
      f[h * 4 + 2] = v.z; f[h * 4 + 3] = v.w;
    }
    u16 o[8];
#pragma unroll
    for (int j = 0; j < 8; ++j) o[j] = f2bf(f[j]);
    *(short8*)(Wt + (size_t)(n0 + n) * HDIM + k0 + kq * 8) = *(short8*)o;
  }
}
__global__ void k_transpose_w(const float* __restrict__ W, u16* __restrict__ Wt) {
  transpose_body(W, Wt);
}
__global__ void k_transpose_all(const float* __restrict__ W0,
                                const float* __restrict__ W1,
                                const float* __restrict__ W2,
                                const float* __restrict__ W3,
                                u16* __restrict__ Wt) {
  const float* W = (blockIdx.z == 0) ? W0 : (blockIdx.z == 1) ? W1
                 : (blockIdx.z == 2) ? W2 : W3;
  transpose_body(W, Wt + (size_t)blockIdx.z * T_SEQ * HDIM);
}

// ---------------- GEMM epilogue helpers ------------------------------------
__device__ __forceinline__ void epi_rope(
    const f32x4 (&acc)[8][4], char* L, int tid, int lr, int lko,
    int wr, int wc, int bm, int bnl, u16* __restrict__ O,
    float* __restrict__ KEYS, bool qscale, const float* __restrict__ ropetab) {
#pragma unroll
  for (int n = 0; n < 4; ++n) {
    int lcol = wc * 64 + n * 16 + lr;
#pragma unroll
    for (int m = 0; m < 8; ++m) {
      int r0 = wr * 128 + m * 16 + lko * 4;
#pragma unroll
      for (int r = 0; r < 4; ++r) {
        int lrow = r0 + r;
        *(u16*)(L + lrow * 512 + ((lcol * 2) ^ ((lrow & 7) << 4))) =
            f2bf(acc[m][n][r]);
      }
    }
  }
  __syncthreads();
  const int hsel = tid >> 8, t2 = tid & 255;
  const int l16 = t2 & 15, rg = t2 >> 4;
  const size_t hbase = (size_t)((bnl >> 7) + hsel) * ((size_t)T_SEQ * HEADD);
#pragma unroll
  for (int ps = 0; ps < 16; ++ps) {
    int lrow = rg + ps * 16;
    short8 v = *(const short8*)(L + lrow * 512 +
                                ((hsel * 256 + l16 * 16) ^ ((lrow & 7) << 4)));
    unsigned* vw = (unsigned*)&v;
    unsigned pw[4];
#pragma unroll
    for (int w = 0; w < 4; ++w) pw[w] = __shfl_xor(vw[w], 8);
    const u16* vh = (const u16*)vw;
    const u16* ph = (const u16*)pw;
    int trow = bm + lrow;
    float cs[8], sn[8];
    const float* tb = ropetab + (size_t)trow * 128 + ((l16 & 7) << 4);
#pragma unroll
    for (int j2 = 0; j2 < 4; ++j2) {
      float4 v4 = *(const float4*)(tb + j2 * 4);
      cs[2 * j2] = v4.x;     sn[2 * j2] = v4.y;
      cs[2 * j2 + 1] = v4.z; sn[2 * j2 + 1] = v4.w;
    }
    float o8[8];
#pragma unroll
    for (int j = 0; j < 8; ++j) {
      float x = b2f(vh[j]), y = b2f(ph[j]);
      float r = (l16 < 8) ? x * cs[j] - y * sn[j] : x * cs[j] + y * sn[j];
      if (qscale) r *= 0.12751741530082662f;   // log2(e)/sqrt(128)
      o8[j] = r;
    }
    u16 ob[8];
#pragma unroll
    for (int j = 0; j < 8; ++j) ob[j] = f2bf(o8[j]);
    *(short8*)(O + hbase + (size_t)trow * HEADD + l16 * 8) = *(short8*)ob;
    if (KEYS) {
      f32x4 a, b;
      a[0] = o8[0]; a[1] = o8[1]; a[2] = o8[2]; a[3] = o8[3];
      b[0] = o8[4]; b[1] = o8[5]; b[2] = o8[6]; b[3] = o8[7];
      *(f32x4*)(KEYS + hbase + (size_t)trow * HEADD + l16 * 8) = a;
      *(f32x4*)(KEYS + hbase + (size_t)trow * HEADD + l16 * 8 + 4) = b;
    }
  }
}

__device__ __forceinline__ void epi_v(
    const f32x4 (&acc)[8][4], char* L, int lane, int wave, int lr, int lko,
    int wr, int wc, int bm, int bnl, u16* __restrict__ VT,
    float* __restrict__ VALS) {
#pragma unroll
  for (int p = 0; p < 2; ++p) {
    if (wr == p) {
#pragma unroll
      for (int n = 0; n < 4; ++n) {
        int lcol = wc * 64 + n * 16 + lr;
#pragma unroll
        for (int m = 0; m < 8; ++m) {
          int r0 = m * 16 + lko * 4;
#pragma unroll
          for (int r = 0; r < 4; ++r) {
            int lrow = r0 + r;
            *(float*)(L + lrow * 1024 + ((lcol * 4) ^ ((lrow & 7) << 4))) =
                acc[m][n][r];
          }
        }
      }
    }
    __syncthreads();
    const int hsel2 = lane >> 5, l32 = lane & 31;
    const size_t hb = (size_t)((bnl >> 7) + hsel2) * ((size_t)T_SEQ * HEADD);
#pragma unroll
    for (int jj = 0; jj < 16; ++jj) {
      int lrow = wave + jj * 8;
      float4 v = *(const float4*)(L + lrow * 1024 +
                                  ((lane * 16) ^ ((lrow & 7) << 4)));
      *(float4*)(VALS + hb + (size_t)(bm + p * 128 + lrow) * HEADD + l32 * 4) = v;
    }
    __syncthreads();
  }
#pragma unroll
  for (int n = 0; n < 4; ++n) {
    int cl = wc * 64 + n * 16 + lr;
    int sw = (cl & 7) << 4;
#pragma unroll
    for (int m = 0; m < 8; ++m) {
      int row2 = (wr * 128 + m * 16 + lko * 4) * 2;
      u16x4 pk;
      pk.x = f2bf(acc[m][n][0]); pk.y = f2bf(acc[m][n][1]);
      pk.z = f2bf(acc[m][n][2]); pk.w = f2bf(acc[m][n][3]);
      *(u16x4*)(L + cl * 512 + (row2 ^ sw)) = pk;
    }
  }
  __syncthreads();
  const int l31 = lane & 31, hi = lane >> 5;
#pragma unroll
  for (int i = 0; i < 16; ++i) {
    int cl = i * 16 + wave * 2 + hi;
    int sw = (cl & 7) << 4;
    short8 v = *(const short8*)(L + cl * 512 + ((l31 * 16) ^ sw));
    int colg = bnl + cl;
    size_t dst = (size_t)(colg >> 7) * ((size_t)HEADD * T_SEQ)
               + (size_t)(colg & 127) * T_SEQ + (size_t)bm + l31 * 8;
    *(short8*)(VT + dst) = v;
  }
}

// ---------------- 256^2 8-phase GEMM (depth-2, vmcnt(4) — final) -----------
// MODE 1: f32 row-major; MODE 2: V; MODE 3: K; MODE 4: Q
template <int MODE>
__global__ __launch_bounds__(512, 2)
void k_gemm256(const u16* __restrict__ A, const u16* __restrict__ Bt,
               void* __restrict__ Cout, void* __restrict__ Cout2,
               const float* __restrict__ ropetab) {
  constexpr int NT = HDIM / 64;   // 64 K-tiles
  __shared__ u16 lds[65536];      // 128 KiB
  char* L = (char*)lds;
  const int tid = threadIdx.x, lane = tid & 63, wave = tid >> 6;
  const int lr = lane & 15, lko = lane >> 4;
  const int wr = wave >> 2, wc = wave & 3;     // 2M x 4N wave grid

  const int bsw = ((blockIdx.x & 7) << 5) | (blockIdx.x >> 3);
  const int bm = (bsw >> 4) * 256, bn = (bsw & 15) * 256;

  const char* Ag = (const char*)A;
  const char* Bg = (const char*)Bt;

  const int p0 = tid * 16, p1 = p0 + 8192;
  const int pr0 = p0 >> 7, pr1 = p1 >> 7;
  const int c0 = (p0 & 127) ^ ((pr0 & 7) << 4);
  const int c1 = (p1 & 127) ^ ((pr1 & 7) << 4);

#define STG(lb, G, gr, kt)                                                  \
  {                                                                         \
    GLOAD16((G) + (size_t)((gr) + pr0) * 8192 + (size_t)(kt) * 128 + c0,    \
            L + (lb) + p0);                                                 \
    GLOAD16((G) + (size_t)((gr) + pr1) * 8192 + (size_t)(kt) * 128 + c1,    \
            L + (lb) + p1);                                                 \
  }

  f32x4 acc[8][4] = {};

  STG(0,             Ag, bm,       0);
  STG(16384,         Ag, bm + 128, 0);
  STG(65536,         Bg, bn,       0);
  STG(65536 + 16384, Bg, bn + 128, 0);
  STG(65536 + 32768,         Bg, bn,       1);
  STG(65536 + 32768 + 16384, Bg, bn + 128, 1);
  asm volatile("s_waitcnt vmcnt(4)" ::: "memory");
  __builtin_amdgcn_s_barrier();

  for (int t = 0; t < NT; ++t) {
    const int d = t & 1;
    const bool sA = (t + 1 < NT), sB = (t + 2 < NT);
    const char* Ab = L + d * 32768 + wr * 16384;
    const char* Bb = L + 65536 + d * 32768 + (wc >> 1) * 16384;
    const int brow = (wc & 1) * 64;

    short8 af[4][2], bf0[2][2], bf1[2][2];

    // ---- P0
#pragma unroll
    for (int m = 0; m < 4; ++m)
#pragma unroll
      for (int kk = 0; kk < 2; ++kk) {
        int row = m * 16 + lr;
        af[m][kk] = *(const short8*)(Ab + row * 128 +
                                     ((kk * 64 + lko * 16) ^ ((row & 7) << 4)));
      }
#pragma unroll
    for (int n = 0; n < 2; ++n)
#pragma unroll
      for (int kk = 0; kk < 2; ++kk) {
        int row = brow + n * 16 + lr;
        bf0[n][kk] = *(const short8*)(Bb + row * 128 +
                                      ((kk * 64 + lko * 16) ^ ((row & 7) << 4)));
      }
    if (sA) STG((d ^ 1) * 32768, Ag, bm, t + 1);
    __builtin_amdgcn_s_barrier();
    __builtin_amdgcn_s_setprio(1);
#pragma unroll
    for (int m = 0; m < 4; ++m)
#pragma unroll
      for (int n = 0; n < 2; ++n)
#pragma unroll
        for (int kk = 0; kk < 2; ++kk)
          acc[m][n] = __builtin_amdgcn_mfma_f32_16x16x32_bf16(
              af[m][kk], bf0[n][kk], acc[m][n], 0, 0, 0);
    __builtin_amdgcn_s_setprio(0);
    __builtin_amdgcn_s_barrier();

    // ---- P1
#pragma unroll
    for (int n = 0; n < 2; ++n)
#pragma unroll
      for (int kk = 0; kk < 2; ++kk) {
        int row = brow + (n + 2) * 16 + lr;
        bf1[n][kk] = *(const short8*)(Bb + row * 128 +
                                      ((kk * 64 + lko * 16) ^ ((row & 7) << 4)));
      }
    if (sA) STG((d ^ 1) * 32768 + 16384, Ag, bm + 128, t + 1);
    __builtin_amdgcn_s_barrier();
    __builtin_amdgcn_s_setprio(1);
#pragma unroll
    for (int m = 0; m < 4; ++m)
#pragma unroll
      for (int n = 0; n < 2; ++n)
#pragma unroll
        for (int kk = 0; kk < 2; ++kk)
          acc[m][n + 2] = __builtin_amdgcn_mfma_f32_16x16x32_bf16(
              af[m][kk], bf1[n][kk], acc[m][n + 2], 0, 0, 0);
    __builtin_amdgcn_s_setprio(0);
    __builtin_amdgcn_s_barrier();

    // ---- P2
#pragma unroll
    for (int m = 0; m < 4; ++m)
#pragma unroll
      for (int kk = 0; kk < 2; ++kk) {
        int row = (m + 4) * 16 + lr;
        af[m][kk] = *(const short8*)(Ab + row * 128 +
                                     ((kk * 64 + lko * 16) ^ ((row & 7) << 4)));
      }
    if (sB) STG(65536 + d * 32768, Bg, bn, t + 2);
    __builtin_amdgcn_s_barrier();
    __builtin_amdgcn_s_setprio(1);
#pragma unroll
    for (int m = 0; m < 4; ++m)
#pragma unroll
      for (int n = 0; n < 2; ++n)
#pragma unroll
        for (int kk = 0; kk < 2; ++kk)
          acc[m + 4][n + 2] = __builtin_amdgcn_mfma_f32_16x16x32_bf16(
              af[m][kk], bf1[n][kk], acc[m + 4][n + 2], 0, 0, 0);
    __builtin_amdgcn_s_setprio(0);
    __builtin_amdgcn_s_barrier();

    // ---- P3
    if (sB) STG(65536 + d * 32768 + 16384, Bg, bn + 128, t + 2);
    __builtin_amdgcn_s_barrier();
    __builtin_amdgcn_s_setprio(1);
#pragma unroll
    for (int m = 0; m < 4; ++m)
#pragma unroll
      for (int n = 0; n < 2; ++n)
#pragma unroll
        for (int kk = 0; kk < 2; ++kk)
          acc[m + 4][n] = __builtin_amdgcn_mfma_f32_16x16x32_bf16(
              af[m][kk], bf0[n][kk], acc[m + 4][n], 0, 0, 0);
    __builtin_amdgcn_s_setprio(0);
    if (sB)      asm volatile("s_waitcnt vmcnt(4)" ::: "memory");
    else if (sA) asm volatile("s_waitcnt vmcnt(0)" ::: "memory");
    __builtin_amdgcn_s_barrier();
  }
#undef STG

  if (MODE == 1) {
    float* O = (float*)Cout;
#pragma unroll
    for (int p = 0; p < 2; ++p) {
      if (wr == p) {
#pragma unroll
        for (int n = 0; n < 4; ++n) {
          int lcol = wc * 64 + n * 16 + lr;
#pragma unroll
          for (int m = 0; m < 8; ++m) {
            int r0 = m * 16 + lko * 4;
#pragma unroll
            for (int r = 0; r < 4; ++r) {
              int lrow = r0 + r;
              *(float*)(L + lrow * 1024 + ((lcol * 4) ^ ((lrow & 7) << 4))) =
                  acc[m][n][r];
            }
          }
        }
      }
      __syncthreads();
#pragma unroll
      for (int jj = 0; jj < 16; ++jj) {
        int lrow = wave + jj * 8;
        float4 v = *(const float4*)(L + lrow * 1024 +
                                    ((lane * 16) ^ ((lrow & 7) << 4)));
        *(float4*)(O + (size_t)(bm + p * 128 + lrow) * HDIM + bn + lane * 4) = v;
      }
      __syncthreads();
    }
  } else if (MODE == 2) {
    epi_v(acc, L, lane, wave, lr, lko, wr, wc, bm, bn,
          (u16*)Cout, (float*)Cout2);
  } else if (MODE == 3) {
    epi_rope(acc, L, tid, lr, lko, wr, wc, bm, bn,
             (u16*)Cout, (float*)Cout2, false, ropetab);
  } else {
    epi_rope(acc, L, tid, lr, lko, wr, wc, bm, bn,
             (u16*)Cout, nullptr, true, ropetab);
  }
}

// ---------------- flash attention, 8-wave 32x32, KVBLK=128 -----------------
__global__ __launch_bounds__(512, 2)
void k_flash3(const u16* __restrict__ Q, const u16* __restrict__ K,
              const u16* __restrict__ Vt, u16* __restrict__ Oattn) {
  constexpr int NTI = T_SEQ / 128;   // 32 tiles
  __shared__ u16 Ks[2][128 * 128];   // 2 x 32 KiB
  __shared__ u16 Vs[2][128 * 128];   // 2 x 32 KiB
  const int tid = threadIdx.x, lane = tid & 63, wave = tid >> 6;
  const int l31 = lane & 31, hi = lane >> 5;
  const int head = blockIdx.x >> 4, qb = blockIdx.x & 15;
  const int q0 = qb * 256 + wave * 32;
  const size_t hoff = (size_t)head * T_SEQ * HEADD;
  const char* Kg = (const char*)(K + hoff);
  const char* Vg = (const char*)(Vt + hoff);
  char* KsB = (char*)Ks;
  char* VsB = (char*)Vs;

  short8 qf[8];
#pragma unroll
  for (int ks = 0; ks < 8; ++ks)
    qf[ks] = *(const short8*)(Q + hoff + (size_t)(q0 + l31) * HEADD + ks * 16 + hi * 8);

  f32x16 o[4] = {};
  float mrun = -1e30f, lrun = 0.f;

  int kc[4], vc[4];
  size_t ksrc_row[4], vsrc_row[4];
#pragma unroll
  for (int c = 0; c < 4; ++c) {
    int p = tid * 16 + c * 8192;
    int kr = p >> 8;
    kc[c] = (p & 255) ^ ((kr & 7) << 4);
    ksrc_row[c] = (size_t)kr * 256;
    int vr = p >> 8;
    vc[c] = (p & 255) ^ ((vr & 7) << 4);
    vsrc_row[c] = (size_t)vr * (T_SEQ * 2);
  }

#define STAGE(buf, jt)                                                     \
  {                                                                        \
    _Pragma("unroll")                                                      \
    for (int c = 0; c < 4; ++c) {                                          \
      int p = tid * 16 + c * 8192;                                         \
      GLOAD16(Kg + (size_t)(jt) * 32768 + ksrc_row[c] + kc[c],             \
              KsB + (buf) * 32768 + p);                                    \
      GLOAD16(Vg + vsrc_row[c] + (size_t)(jt) * 256 + vc[c],               \
              VsB + (buf) * 32768 + p);                                    \
    }                                                                      \
  }

  STAGE(0, 0);
  __syncthreads();
  int cur = 0;

  for (int jt = 0; jt < NTI; ++jt) {
    if (jt + 1 < NTI) STAGE(cur ^ 1, jt + 1);
    const int cb = cur * 32768;

    f32x16 sacc[4] = {};
#pragma unroll
    for (int h2 = 0; h2 < 4; ++h2) {
      int kr = h2 * 32 + l31;
      int swz = (kr & 7) << 4;
#pragma unroll
      for (int ks = 0; ks < 8; ++ks) {
        short8 kf = *(const short8*)(KsB + cb + kr * 256 +
                                     ((ks * 32 + hi * 16) ^ swz));
        sacc[h2] = __builtin_amdgcn_mfma_f32_32x32x16_bf16(kf, qf[ks],
                                                           sacc[h2], 0, 0, 0);
      }
    }

    float t16[16];
#pragma unroll
    for (int r = 0; r < 16; ++r)
      t16[r] = fmaxf(fmaxf(sacc[0][r], sacc[1][r]),
                     fmaxf(sacc[2][r], sacc[3][r]));
#pragma unroll
    for (int s = 8; s >= 1; s >>= 1)
#pragma unroll
      for (int r = 0; r < 8; ++r)
        if (r < s) t16[r] = fmaxf(t16[r], t16[r + s]);
    float mt;
    {
      unsigned ma = __float_as_uint(t16[0]), mb = ma;
      permswap(ma, mb);
      mt = fmaxf(__uint_as_float(ma), __uint_as_float(mb));
    }

    if (__any(mt > mrun + 11.5f)) {     // 8 * log2(e)
      float mnew = fmaxf(mrun, mt);
      float rs = fexp2(mrun - mnew);
      mrun = mnew;
      lrun *= rs;
#pragma unroll
      for (int reg = 0; reg < 16; ++reg) {
        float rb = __shfl(rs, (reg & 3) + 8 * (reg >> 2) + 4 * hi);
#pragma unroll
        for (int d0 = 0; d0 < 4; ++d0) o[d0][reg] *= rb;
      }
    }

    // exp + row-sum with 4 independent accumulators (breaks the 128-add
    // serial dependency chain; static indices -> registers)
    float psv[4] = {0.f, 0.f, 0.f, 0.f};
#pragma unroll
    for (int h2 = 0; h2 < 4; ++h2)
#pragma unroll
      for (int r = 0; r < 16; ++r) {
        float e = fexp2(sacc[h2][r] - mrun);
        psv[r & 3] += e;
        sacc[h2][r] = e;
      }
    lrun += (psv[0] + psv[1]) + (psv[2] + psv[3]);

#pragma unroll
    for (int half = 0; half < 2; ++half) {
      short8 pa[4];
#pragma unroll
      for (int h2 = 0; h2 < 2; ++h2)
#pragma unroll
        for (int kk = 0; kk < 2; ++kk) {
          const f32x16& sh = sacc[2 * half + h2];
          unsigned w[4];
#pragma unroll
          for (int m = 0; m < 2; ++m) {
            unsigned A = cvtpk(sh[8 * kk + 2 * m], sh[8 * kk + 2 * m + 1]);
            unsigned B = cvtpk(sh[8 * kk + 4 + 2 * m], sh[8 * kk + 5 + 2 * m]);
            permswap(A, B);
            w[m] = A; w[2 + m] = B;
          }
          unsigned* pw = (unsigned*)&pa[2 * h2 + kk];
          pw[0] = w[0]; pw[1] = w[1]; pw[2] = w[2]; pw[3] = w[3];
        }
#pragma unroll
      for (int d0 = 0; d0 < 4; ++d0) {
        int vr = d0 * 32 + l31;
        int swz = (vr & 7) << 4;
#pragma unroll
        for (int ks = 0; ks < 4; ++ks) {
          short8 vf = *(const short8*)(VsB + cb + vr * 256 +
                                       (((half * 4 + ks) * 32 + hi * 16) ^ swz));
          o[d0] = __builtin_amdgcn_mfma_f32_32x32x16_bf16(pa[ks], vf,
                                                          o[d0], 0, 0, 0);
        }
      }
    }
    __syncthreads();
    cur ^= 1;
  }

  float lt;
  {
    unsigned la = __float_as_uint(lrun), lb = la;
    permswap(la, lb);
    lt = __uint_as_float(la) + __uint_as_float(lb);
  }
  float rinv = 1.f / lt;
#pragma unroll
  for (int reg = 0; reg < 16; ++reg) {
    int crow = (reg & 3) + 8 * (reg >> 2) + 4 * hi;
    float rb = __shfl(rinv, crow);
    size_t trow = (size_t)(q0 + crow) * HDIM + head * 128;
#pragma unroll
    for (int d0 = 0; d0 < 4; ++d0)
      Oattn[trow + d0 * 32 + l31] = f2bf(o[d0][reg] * rb);
  }
#undef STAGE
}

}  // namespace

extern "C" void kernel_launch(void* const* d_in, const int* in_sizes, int n_in,
                              void* d_out, int out_size, void* d_ws, size_t ws_size,
                              hipStream_t stream) {
  (void)in_sizes; (void)n_in; (void)out_size;
  const float* hs  = (const float*)d_in[0];
  const int*   pos = (const int*)d_in[2];
  const float* Wq  = (const float*)d_in[3];
  const float* Wk  = (const float*)d_in[4];
  const float* Wv  = (const float*)d_in[5];
  const float* Wo  = (const float*)d_in[6];

  float* out_res  = (float*)d_out;
  float* out_keys = out_res + (size_t)T_SEQ * HDIM;
  float* out_vals = out_keys + (size_t)NHEADS * T_SEQ * HEADD;

  const size_t NEL = (size_t)T_SEQ * HDIM;   // 16.7M elems = 32 MiB bf16
  dim3 b256(256);
  dim3 b512(512);
  dim3 gemmgrid(256);

  const bool big = ws_size >= (8 * NEL * 2 + (size_t)(2 << 20));

  if (big) {
    u16* Xb  = (u16*)d_ws;
    u16* Wt4 = Xb + NEL;
    u16* qb  = Wt4 + 4 * NEL;
    u16* kb  = qb + NEL;
    u16* vt  = kb + NEL;
    float* ropetab = (float*)(vt + NEL);

    const int nconv = (int)(NEL / 4 / 256);             // 16384
    k_prep<<<dim3(nconv + T_SEQ * 64 / 256), b256, 0, stream>>>(
        (const float4*)hs, (u16x4*)Xb, nconv, (int)(NEL / 4), pos, ropetab);
    k_transpose_all<<<dim3(HDIM / 64, HDIM / 64, 4), b256, 0, stream>>>(
        Wq, Wk, Wv, Wo, Wt4);

    k_gemm256<4><<<gemmgrid, b512, 0, stream>>>(Xb, Wt4, qb, nullptr, ropetab);
    k_gemm256<3><<<gemmgrid, b512, 0, stream>>>(Xb, Wt4 + NEL, kb, out_keys,
                                                ropetab);
    k_gemm256<2><<<gemmgrid, b512, 0, stream>>>(Xb, Wt4 + 2 * NEL, vt, out_vals,
                                                nullptr);
    k_flash3<<<dim3(NHEADS * (T_SEQ / 256)), b512, 0, stream>>>(qb, kb, vt, Xb);
    k_gemm256<1><<<gemmgrid, b512, 0, stream>>>(Xb, Wt4 + 3 * NEL, d_out,
                                                nullptr, nullptr);
  } else {
    u16* Xb = (u16*)d_ws;
    u16* Wt = Xb + NEL;
    u16* qb = Wt + NEL;
    u16* kb = qb + NEL;
    u16* vt = kb + NEL;
    float* ropetab = (float*)vt;
    dim3 tw(HDIM / 64, HDIM / 64);

    k_f32_to_bf16<<<dim3((int)(NEL / 4 / 256)), b256, 0, stream>>>(
        (const float4*)hs, (u16x4*)Xb, (int)(NEL / 4));
    k_rope_table<<<dim3(T_SEQ * 64 / 256), b256, 0, stream>>>(pos, ropetab);

    k_transpose_w<<<tw, b256, 0, stream>>>(Wq, Wt);
    k_gemm256<4><<<gemmgrid, b512, 0, stream>>>(Xb, Wt, qb, nullptr, ropetab);
    k_transpose_w<<<tw, b256, 0, stream>>>(Wk, Wt);
    k_gemm256<3><<<gemmgrid, b512, 0, stream>>>(Xb, Wt, kb, out_keys, ropetab);

    k_transpose_w<<<tw, b256, 0, stream>>>(Wv, Wt);
    k_gemm256<2><<<gemmgrid, b512, 0, stream>>>(Xb, Wt, vt, out_vals, nullptr);

    k_flash3<<<dim3(NHEADS * (T_SEQ / 256)), b512, 0, stream>>>(qb, kb, vt, Xb);

    k_transpose_w<<<tw, b256, 0, stream>>>(Wo, Wt);
    k_gemm256<1><<<gemmgrid, b512, 0, stream>>>(Xb, Wt, d_out, nullptr, nullptr);
  }
}

// Round 20
// 843.829 us; speedup vs baseline: 1.0241x; 1.0058x over previous
//
#include <hip/hip_runtime.h>

// LlamaAttention prefill, MI355X/gfx950.
// R20 vs R19 (single change): flash block->(head,qb) mapping made XCD-aware
// (T1). Old: head=bx>>4 -> a head's 16 q-blocks round-robin across all 8
// XCDs, each XCD's L2 refetches the same 2MB K/V (FETCH 278MB vs 96MB ideal,
// spills L3). New: head=(bx&7)+8*((bx>>3)>>4), qb=(bx>>3)&15 -> each XCD
// owns 4 whole heads; K/V L2-resident per head. Bijective. All else = R19.

namespace {

constexpr int T_SEQ  = 4096;
constexpr int HDIM   = 4096;
constexpr int NHEADS = 32;
constexpr int HEADD  = 128;

typedef unsigned short u16;
typedef short short8 __attribute__((ext_vector_type(8)));   // 8 x bf16 (4 VGPR)
typedef float f32x4 __attribute__((ext_vector_type(4)));
typedef float f32x16 __attribute__((ext_vector_type(16)));
typedef unsigned short u16x4 __attribute__((ext_vector_type(4)));
typedef unsigned uint2v __attribute__((ext_vector_type(2)));

__device__ __forceinline__ u16 f2bf(float x) {
  unsigned u = __float_as_uint(x);
  u += 0x7fffu + ((u >> 16) & 1u);   // round-to-nearest-even
  return (u16)(u >> 16);
}
__device__ __forceinline__ float b2f(u16 x) {
  return __uint_as_float(((unsigned)x) << 16);
}

// native 2^x: single v_exp_f32
__device__ __forceinline__ float fexp2(float x) {
#if __has_builtin(__builtin_amdgcn_exp2f)
  return __builtin_amdgcn_exp2f(x);
#else
  float r;
  asm("v_exp_f32 %0, %1" : "=v"(r) : "v"(x));
  return r;
#endif
}

// v_permlane32_swap_b32: new a = [a_lo | b_lo], new b = [a_hi | b_hi]
__device__ __forceinline__ void permswap(unsigned& a, unsigned& b) {
#if __has_builtin(__builtin_amdgcn_permlane32_swap)
  uint2v r = __builtin_amdgcn_permlane32_swap(a, b, false, false);
  a = r.x; b = r.y;
#else
  asm volatile("s_nop 1\n\tv_permlane32_swap_b32 %0, %1\n\ts_nop 1"
               : "+v"(a), "+v"(b));
#endif
}
__device__ __forceinline__ unsigned cvtpk(float lo, float hi) {
  unsigned r;
  asm("v_cvt_pk_bf16_f32 %0, %1, %2" : "=v"(r) : "v"(lo), "v"(hi));
  return r;
}

#define GLOAD16(gp, lp)                                              \
  __builtin_amdgcn_global_load_lds(                                  \
      (const __attribute__((address_space(1))) void*)(gp),           \
      (__attribute__((address_space(3))) void*)(lp), 16, 0, 0)

// ---------------- f32 -> bf16 convert (+ rope table in tail blocks) --------
__global__ void k_prep(const float4* __restrict__ in, u16x4* __restrict__ out,
                       int nconvblk, int n4,
                       const int* __restrict__ pos, float* __restrict__ tab) {
  if ((int)blockIdx.x < nconvblk) {
    int i = blockIdx.x * 256 + threadIdx.x;
    if (i >= n4) return;
    float4 v = in[i];
    u16x4 o;
    o.x = f2bf(v.x); o.y = f2bf(v.y); o.z = f2bf(v.z); o.w = f2bf(v.w);
    out[i] = o;
  } else {
    int idx = (blockIdx.x - nconvblk) * 256 + threadIdx.x;  // 0 .. T*64-1
    int t = idx >> 6, f = idx & 63;
    float inv = exp2f(-(float)f * 0.20762050593045951f);    // log2(10000)/64
    float ang = (float)pos[t] * inv;
    float sn, cs;
    sincosf(ang, &sn, &cs);
    tab[idx * 2] = cs;
    tab[idx * 2 + 1] = sn;
  }
}
__global__ void k_rope_table(const int* __restrict__ pos, float* __restrict__ tab) {
  int idx = blockIdx.x * 256 + threadIdx.x;
  int t = idx >> 6, f = idx & 63;
  float inv = exp2f(-(float)f * 0.20762050593045951f);
  float ang = (float)pos[t] * inv;
  float sn, cs;
  sincosf(ang, &sn, &cs);
  tab[idx * 2] = cs;
  tab[idx * 2 + 1] = sn;
}
__global__ void k_f32_to_bf16(const float4* __restrict__ in,
                              u16x4* __restrict__ out, int n4) {
  int i = blockIdx.x * 256 + threadIdx.x;
  if (i >= n4) return;
  float4 v = in[i];
  u16x4 o;
  o.x = f2bf(v.x); o.y = f2bf(v.y); o.z = f2bf(v.z); o.w = f2bf(v.w);
  out[i] = o;
}

// ---------------- W [K][N] f32 -> Wt [N][K] bf16, 64x64 tiles --------------
__device__ __forceinline__ void transpose_body(const float* __restrict__ W,
                                               u16* __restrict__ Wt) {
  __shared__ float tile[64 * 64];   // 16 KiB
  char* Lb = (char*)tile;
  int n0 = blockIdx.x * 64, k0 = blockIdx.y * 64;
  int tid = threadIdx.x;            // 256
  int tx = tid & 15, ky = tid >> 4;
#pragma unroll
  for (int i = 0; i < 4; ++i) {
    int k = ky + i * 16;
    float4 v = *(const float4*)(W + (size_t)(k0 + k) * HDIM + n0 + tx * 4);
#pragma unroll
    for (int j = 0; j < 4; ++j) {
      int n = tx * 4 + j;
      *(float*)(Lb + n * 256 + ((k * 4) ^ ((n & 7) << 4))) = ((const float*)&v)[j];
    }
  }
  __syncthreads();
  int kq = tid & 7, ny = tid >> 3;
#pragma unroll
  for (int p = 0; p < 2; ++p) {
    int n = ny + p * 32;
    int sw = (n & 7) << 4;
    float f[8];
#pragma unroll
    for (int h = 0; h < 2; ++h) {
      float4 v = *(const float4*)(Lb + n * 256 + ((kq * 32 + h * 16) ^ sw));
      f[h * 4 + 0] = v.x; f[h * 4 + 1] = v.y;
      f[h * 4 + 2] = v.z; f[h * 4 + 3] = v.w;
    }
    u16 o[8];
#pragma unroll
    for (int j = 0; j < 8; ++j) o[j] = f2bf(f[j]);
    *(short8*)(Wt + (size_t)(n0 + n) * HDIM + k0 + kq * 8) = *(short8*)o;
  }
}
__global__ void k_transpose_w(const float* __restrict__ W, u16* __restrict__ Wt) {
  transpose_body(W, Wt);
}
__global__ void k_transpose_all(const float* __restrict__ W0,
                                const float* __restrict__ W1,
                                const float* __restrict__ W2,
                                const float* __restrict__ W3,
                                u16* __restrict__ Wt) {
  const float* W = (blockIdx.z == 0) ? W0 : (blockIdx.z == 1) ? W1
                 : (blockIdx.z == 2) ? W2 : W3;
  transpose_body(W, Wt + (size_t)blockIdx.z * T_SEQ * HDIM);
}

// ---------------- GEMM epilogue helpers ------------------------------------
__device__ __forceinline__ void epi_rope(
    const f32x4 (&acc)[8][4], char* L, int tid, int lr, int lko,
    int wr, int wc, int bm, int bnl, u16* __restrict__ O,
    float* __restrict__ KEYS, bool qscale, const float* __restrict__ ropetab) {
#pragma unroll
  for (int n = 0; n < 4; ++n) {
    int lcol = wc * 64 + n * 16 + lr;
#pragma unroll
    for (int m = 0; m < 8; ++m) {
      int r0 = wr * 128 + m * 16 + lko * 4;
#pragma unroll
      for (int r = 0; r < 4; ++r) {
        int lrow = r0 + r;
        *(u16*)(L + lrow * 512 + ((lcol * 2) ^ ((lrow & 7) << 4))) =
            f2bf(acc[m][n][r]);
      }
    }
  }
  __syncthreads();
  const int hsel = tid >> 8, t2 = tid & 255;
  const int l16 = t2 & 15, rg = t2 >> 4;
  const size_t hbase = (size_t)((bnl >> 7) + hsel) * ((size_t)T_SEQ * HEADD);
#pragma unroll
  for (int ps = 0; ps < 16; ++ps) {
    int lrow = rg + ps * 16;
    short8 v = *(const short8*)(L + lrow * 512 +
                                ((hsel * 256 + l16 * 16) ^ ((lrow & 7) << 4)));
    unsigned* vw = (unsigned*)&v;
    unsigned pw[4];
#pragma unroll
    for (int w = 0; w < 4; ++w) pw[w] = __shfl_xor(vw[w], 8);
    const u16* vh = (const u16*)vw;
    const u16* ph = (const u16*)pw;
    int trow = bm + lrow;
    float cs[8], sn[8];
    const float* tb = ropetab + (size_t)trow * 128 + ((l16 & 7) << 4);
#pragma unroll
    for (int j2 = 0; j2 < 4; ++j2) {
      float4 v4 = *(const float4*)(tb + j2 * 4);
      cs[2 * j2] = v4.x;     sn[2 * j2] = v4.y;
      cs[2 * j2 + 1] = v4.z; sn[2 * j2 + 1] = v4.w;
    }
    float o8[8];
#pragma unroll
    for (int j = 0; j < 8; ++j) {
      float x = b2f(vh[j]), y = b2f(ph[j]);
      float r = (l16 < 8) ? x * cs[j] - y * sn[j] : x * cs[j] + y * sn[j];
      if (qscale) r *= 0.12751741530082662f;   // log2(e)/sqrt(128)
      o8[j] = r;
    }
    u16 ob[8];
#pragma unroll
    for (int j = 0; j < 8; ++j) ob[j] = f2bf(o8[j]);
    *(short8*)(O + hbase + (size_t)trow * HEADD + l16 * 8) = *(short8*)ob;
    if (KEYS) {
      f32x4 a, b;
      a[0] = o8[0]; a[1] = o8[1]; a[2] = o8[2]; a[3] = o8[3];
      b[0] = o8[4]; b[1] = o8[5]; b[2] = o8[6]; b[3] = o8[7];
      *(f32x4*)(KEYS + hbase + (size_t)trow * HEADD + l16 * 8) = a;
      *(f32x4*)(KEYS + hbase + (size_t)trow * HEADD + l16 * 8 + 4) = b;
    }
  }
}

__device__ __forceinline__ void epi_v(
    const f32x4 (&acc)[8][4], char* L, int lane, int wave, int lr, int lko,
    int wr, int wc, int bm, int bnl, u16* __restrict__ VT,
    float* __restrict__ VALS) {
#pragma unroll
  for (int p = 0; p < 2; ++p) {
    if (wr == p) {
#pragma unroll
      for (int n = 0; n < 4; ++n) {
        int lcol = wc * 64 + n * 16 + lr;
#pragma unroll
        for (int m = 0; m < 8; ++m) {
          int r0 = m * 16 + lko * 4;
#pragma unroll
          for (int r = 0; r < 4; ++r) {
            int lrow = r0 + r;
            *(float*)(L + lrow * 1024 + ((lcol * 4) ^ ((lrow & 7) << 4))) =
                acc[m][n][r];
          }
        }
      }
    }
    __syncthreads();
    const int hsel2 = lane >> 5, l32 = lane & 31;
    const size_t hb = (size_t)((bnl >> 7) + hsel2) * ((size_t)T_SEQ * HEADD);
#pragma unroll
    for (int jj = 0; jj < 16; ++jj) {
      int lrow = wave + jj * 8;
      float4 v = *(const float4*)(L + lrow * 1024 +
                                  ((lane * 16) ^ ((lrow & 7) << 4)));
      *(float4*)(VALS + hb + (size_t)(bm + p * 128 + lrow) * HEADD + l32 * 4) = v;
    }
    __syncthreads();
  }
#pragma unroll
  for (int n = 0; n < 4; ++n) {
    int cl = wc * 64 + n * 16 + lr;
    int sw = (cl & 7) << 4;
#pragma unroll
    for (int m = 0; m < 8; ++m) {
      int row2 = (wr * 128 + m * 16 + lko * 4) * 2;
      u16x4 pk;
      pk.x = f2bf(acc[m][n][0]); pk.y = f2bf(acc[m][n][1]);
      pk.z = f2bf(acc[m][n][2]); pk.w = f2bf(acc[m][n][3]);
      *(u16x4*)(L + cl * 512 + (row2 ^ sw)) = pk;
    }
  }
  __syncthreads();
  const int l31 = lane & 31, hi = lane >> 5;
#pragma unroll
  for (int i = 0; i < 16; ++i) {
    int cl = i * 16 + wave * 2 + hi;
    int sw = (cl & 7) << 4;
    short8 v = *(const short8*)(L + cl * 512 + ((l31 * 16) ^ sw));
    int colg = bnl + cl;
    size_t dst = (size_t)(colg >> 7) * ((size_t)HEADD * T_SEQ)
               + (size_t)(colg & 127) * T_SEQ + (size_t)bm + l31 * 8;
    *(short8*)(VT + dst) = v;
  }
}

// ---------------- 256^2 8-phase GEMM (depth-2, vmcnt(4) — final) -----------
// MODE 1: f32 row-major; MODE 2: V; MODE 3: K; MODE 4: Q
template <int MODE>
__global__ __launch_bounds__(512, 2)
void k_gemm256(const u16* __restrict__ A, const u16* __restrict__ Bt,
               void* __restrict__ Cout, void* __restrict__ Cout2,
               const float* __restrict__ ropetab) {
  constexpr int NT = HDIM / 64;   // 64 K-tiles
  __shared__ u16 lds[65536];      // 128 KiB
  char* L = (char*)lds;
  const int tid = threadIdx.x, lane = tid & 63, wave = tid >> 6;
  const int lr = lane & 15, lko = lane >> 4;
  const int wr = wave >> 2, wc = wave & 3;     // 2M x 4N wave grid

  const int bsw = ((blockIdx.x & 7) << 5) | (blockIdx.x >> 3);
  const int bm = (bsw >> 4) * 256, bn = (bsw & 15) * 256;

  const char* Ag = (const char*)A;
  const char* Bg = (const char*)Bt;

  const int p0 = tid * 16, p1 = p0 + 8192;
  const int pr0 = p0 >> 7, pr1 = p1 >> 7;
  const int c0 = (p0 & 127) ^ ((pr0 & 7) << 4);
  const int c1 = (p1 & 127) ^ ((pr1 & 7) << 4);

#define STG(lb, G, gr, kt)                                                  \
  {                                                                         \
    GLOAD16((G) + (size_t)((gr) + pr0) * 8192 + (size_t)(kt) * 128 + c0,    \
            L + (lb) + p0);                                                 \
    GLOAD16((G) + (size_t)((gr) + pr1) * 8192 + (size_t)(kt) * 128 + c1,    \
            L + (lb) + p1);                                                 \
  }

  f32x4 acc[8][4] = {};

  STG(0,             Ag, bm,       0);
  STG(16384,         Ag, bm + 128, 0);
  STG(65536,         Bg, bn,       0);
  STG(65536 + 16384, Bg, bn + 128, 0);
  STG(65536 + 32768,         Bg, bn,       1);
  STG(65536 + 32768 + 16384, Bg, bn + 128, 1);
  asm volatile("s_waitcnt vmcnt(4)" ::: "memory");
  __builtin_amdgcn_s_barrier();

  for (int t = 0; t < NT; ++t) {
    const int d = t & 1;
    const bool sA = (t + 1 < NT), sB = (t + 2 < NT);
    const char* Ab = L + d * 32768 + wr * 16384;
    const char* Bb = L + 65536 + d * 32768 + (wc >> 1) * 16384;
    const int brow = (wc & 1) * 64;

    short8 af[4][2], bf0[2][2], bf1[2][2];

    // ---- P0
#pragma unroll
    for (int m = 0; m < 4; ++m)
#pragma unroll
      for (int kk = 0; kk < 2; ++kk) {
        int row = m * 16 + lr;
        af[m][kk] = *(const short8*)(Ab + row * 128 +
                                     ((kk * 64 + lko * 16) ^ ((row & 7) << 4)));
      }
#pragma unroll
    for (int n = 0; n < 2; ++n)
#pragma unroll
      for (int kk = 0; kk < 2; ++kk) {
        int row = brow + n * 16 + lr;
        bf0[n][kk] = *(const short8*)(Bb + row * 128 +
                                      ((kk * 64 + lko * 16) ^ ((row & 7) << 4)));
      }
    if (sA) STG((d ^ 1) * 32768, Ag, bm, t + 1);
    __builtin_amdgcn_s_barrier();
    __builtin_amdgcn_s_setprio(1);
#pragma unroll
    for (int m = 0; m < 4; ++m)
#pragma unroll
      for (int n = 0; n < 2; ++n)
#pragma unroll
        for (int kk = 0; kk < 2; ++kk)
          acc[m][n] = __builtin_amdgcn_mfma_f32_16x16x32_bf16(
              af[m][kk], bf0[n][kk], acc[m][n], 0, 0, 0);
    __builtin_amdgcn_s_setprio(0);
    __builtin_amdgcn_s_barrier();

    // ---- P1
#pragma unroll
    for (int n = 0; n < 2; ++n)
#pragma unroll
      for (int kk = 0; kk < 2; ++kk) {
        int row = brow + (n + 2) * 16 + lr;
        bf1[n][kk] = *(const short8*)(Bb + row * 128 +
                                      ((kk * 64 + lko * 16) ^ ((row & 7) << 4)));
      }
    if (sA) STG((d ^ 1) * 32768 + 16384, Ag, bm + 128, t + 1);
    __builtin_amdgcn_s_barrier();
    __builtin_amdgcn_s_setprio(1);
#pragma unroll
    for (int m = 0; m < 4; ++m)
#pragma unroll
      for (int n = 0; n < 2; ++n)
#pragma unroll
        for (int kk = 0; kk < 2; ++kk)
          acc[m][n + 2] = __builtin_amdgcn_mfma_f32_16x16x32_bf16(
              af[m][kk], bf1[n][kk], acc[m][n + 2], 0, 0, 0);
    __builtin_amdgcn_s_setprio(0);
    __builtin_amdgcn_s_barrier();

    // ---- P2
#pragma unroll
    for (int m = 0; m < 4; ++m)
#pragma unroll
      for (int kk = 0; kk < 2; ++kk) {
        int row = (m + 4) * 16 + lr;
        af[m][kk] = *(const short8*)(Ab + row * 128 +
                                     ((kk * 64 + lko * 16) ^ ((row & 7) << 4)));
      }
    if (sB) STG(65536 + d * 32768, Bg, bn, t + 2);
    __builtin_amdgcn_s_barrier();
    __builtin_amdgcn_s_setprio(1);
#pragma unroll
    for (int m = 0; m < 4; ++m)
#pragma unroll
      for (int n = 0; n < 2; ++n)
#pragma unroll
        for (int kk = 0; kk < 2; ++kk)
          acc[m + 4][n + 2] = __builtin_amdgcn_mfma_f32_16x16x32_bf16(
              af[m][kk], bf1[n][kk], acc[m + 4][n + 2], 0, 0, 0);
    __builtin_amdgcn_s_setprio(0);
    __builtin_amdgcn_s_barrier();

    // ---- P3
    if (sB) STG(65536 + d * 32768 + 16384, Bg, bn + 128, t + 2);
    __builtin_amdgcn_s_barrier();
    __builtin_amdgcn_s_setprio(1);
#pragma unroll
    for (int m = 0; m < 4; ++m)
#pragma unroll
      for (int n = 0; n < 2; ++n)
#pragma unroll
        for (int kk = 0; kk < 2; ++kk)
          acc[m + 4][n] = __builtin_amdgcn_mfma_f32_16x16x32_bf16(
              af[m][kk], bf0[n][kk], acc[m + 4][n], 0, 0, 0);
    __builtin_amdgcn_s_setprio(0);
    if (sB)      asm volatile("s_waitcnt vmcnt(4)" ::: "memory");
    else if (sA) asm volatile("s_waitcnt vmcnt(0)" ::: "memory");
    __builtin_amdgcn_s_barrier();
  }
#undef STG

  if (MODE == 1) {
    float* O = (float*)Cout;
#pragma unroll
    for (int p = 0; p < 2; ++p) {
      if (wr == p) {
#pragma unroll
        for (int n = 0; n < 4; ++n) {
          int lcol = wc * 64 + n * 16 + lr;
#pragma unroll
          for (int m = 0; m < 8; ++m) {
            int r0 = m * 16 + lko * 4;
#pragma unroll
            for (int r = 0; r < 4; ++r) {
              int lrow = r0 + r;
              *(float*)(L + lrow * 1024 + ((lcol * 4) ^ ((lrow & 7) << 4))) =
                  acc[m][n][r];
            }
          }
        }
      }
      __syncthreads();
#pragma unroll
      for (int jj = 0; jj < 16; ++jj) {
        int lrow = wave + jj * 8;
        float4 v = *(const float4*)(L + lrow * 1024 +
                                    ((lane * 16) ^ ((lrow & 7) << 4)));
        *(float4*)(O + (size_t)(bm + p * 128 + lrow) * HDIM + bn + lane * 4) = v;
      }
      __syncthreads();
    }
  } else if (MODE == 2) {
    epi_v(acc, L, lane, wave, lr, lko, wr, wc, bm, bn,
          (u16*)Cout, (float*)Cout2);
  } else if (MODE == 3) {
    epi_rope(acc, L, tid, lr, lko, wr, wc, bm, bn,
             (u16*)Cout, (float*)Cout2, false, ropetab);
  } else {
    epi_rope(acc, L, tid, lr, lko, wr, wc, bm, bn,
             (u16*)Cout, nullptr, true, ropetab);
  }
}

// ---------------- flash attention, 8-wave 32x32, KVBLK=128 -----------------
// XCD-aware (head,qb) mapping: each XCD owns 4 whole heads -> K/V L2-resident.
__global__ __launch_bounds__(512, 2)
void k_flash3(const u16* __restrict__ Q, const u16* __restrict__ K,
              const u16* __restrict__ Vt, u16* __restrict__ Oattn) {
  constexpr int NTI = T_SEQ / 128;   // 32 tiles
  __shared__ u16 Ks[2][128 * 128];   // 2 x 32 KiB
  __shared__ u16 Vs[2][128 * 128];   // 2 x 32 KiB
  const int tid = threadIdx.x, lane = tid & 63, wave = tid >> 6;
  const int l31 = lane & 31, hi = lane >> 5;
  const int bx = blockIdx.x;
  const int head = (bx & 7) + 8 * ((bx >> 3) >> 4);   // XCD (bx&7) owns 4 heads
  const int qb = (bx >> 3) & 15;
  const int q0 = qb * 256 + wave * 32;
  const size_t hoff = (size_t)head * T_SEQ * HEADD;
  const char* Kg = (const char*)(K + hoff);
  const char* Vg = (const char*)(Vt + hoff);
  char* KsB = (char*)Ks;
  char* VsB = (char*)Vs;

  short8 qf[8];
#pragma unroll
  for (int ks = 0; ks < 8; ++ks)
    qf[ks] = *(const short8*)(Q + hoff + (size_t)(q0 + l31) * HEADD + ks * 16 + hi * 8);

  f32x16 o[4] = {};
  float mrun = -1e30f, lrun = 0.f;

  int kc[4], vc[4];
  size_t ksrc_row[4], vsrc_row[4];
#pragma unroll
  for (int c = 0; c < 4; ++c) {
    int p = tid * 16 + c * 8192;
    int kr = p >> 8;
    kc[c] = (p & 255) ^ ((kr & 7) << 4);
    ksrc_row[c] = (size_t)kr * 256;
    int vr = p >> 8;
    vc[c] = (p & 255) ^ ((vr & 7) << 4);
    vsrc_row[c] = (size_t)vr * (T_SEQ * 2);
  }

#define STAGE(buf, jt)                                                     \
  {                                                                        \
    _Pragma("unroll")                                                      \
    for (int c = 0; c < 4; ++c) {                                          \
      int p = tid * 16 + c * 8192;                                         \
      GLOAD16(Kg + (size_t)(jt) * 32768 + ksrc_row[c] + kc[c],             \
              KsB + (buf) * 32768 + p);                                    \
      GLOAD16(Vg + vsrc_row[c] + (size_t)(jt) * 256 + vc[c],               \
              VsB + (buf) * 32768 + p);                                    \
    }                                                                      \
  }

  STAGE(0, 0);
  __syncthreads();
  int cur = 0;

  for (int jt = 0; jt < NTI; ++jt) {
    if (jt + 1 < NTI) STAGE(cur ^ 1, jt + 1);
    const int cb = cur * 32768;

    f32x16 sacc[4] = {};
#pragma unroll
    for (int h2 = 0; h2 < 4; ++h2) {
      int kr = h2 * 32 + l31;
      int swz = (kr & 7) << 4;
#pragma unroll
      for (int ks = 0; ks < 8; ++ks) {
        short8 kf = *(const short8*)(KsB + cb + kr * 256 +
                                     ((ks * 32 + hi * 16) ^ swz));
        sacc[h2] = __builtin_amdgcn_mfma_f32_32x32x16_bf16(kf, qf[ks],
                                                           sacc[h2], 0, 0, 0);
      }
    }

    float t16[16];
#pragma unroll
    for (int r = 0; r < 16; ++r)
      t16[r] = fmaxf(fmaxf(sacc[0][r], sacc[1][r]),
                     fmaxf(sacc[2][r], sacc[3][r]));
#pragma unroll
    for (int s = 8; s >= 1; s >>= 1)
#pragma unroll
      for (int r = 0; r < 8; ++r)
        if (r < s) t16[r] = fmaxf(t16[r], t16[r + s]);
    float mt;
    {
      unsigned ma = __float_as_uint(t16[0]), mb = ma;
      permswap(ma, mb);
      mt = fmaxf(__uint_as_float(ma), __uint_as_float(mb));
    }

    if (__any(mt > mrun + 11.5f)) {     // 8 * log2(e)
      float mnew = fmaxf(mrun, mt);
      float rs = fexp2(mrun - mnew);
      mrun = mnew;
      lrun *= rs;
#pragma unroll
      for (int reg = 0; reg < 16; ++reg) {
        float rb = __shfl(rs, (reg & 3) + 8 * (reg >> 2) + 4 * hi);
#pragma unroll
        for (int d0 = 0; d0 < 4; ++d0) o[d0][reg] *= rb;
      }
    }

    // exp + row-sum with 4 independent accumulators
    float psv[4] = {0.f, 0.f, 0.f, 0.f};
#pragma unroll
    for (int h2 = 0; h2 < 4; ++h2)
#pragma unroll
      for (int r = 0; r < 16; ++r) {
        float e = fexp2(sacc[h2][r] - mrun);
        psv[r & 3] += e;
        sacc[h2][r] = e;
      }
    lrun += (psv[0] + psv[1]) + (psv[2] + psv[3]);

#pragma unroll
    for (int half = 0; half < 2; ++half) {
      short8 pa[4];
#pragma unroll
      for (int h2 = 0; h2 < 2; ++h2)
#pragma unroll
        for (int kk = 0; kk < 2; ++kk) {
          const f32x16& sh = sacc[2 * half + h2];
          unsigned w[4];
#pragma unroll
          for (int m = 0; m < 2; ++m) {
            unsigned A = cvtpk(sh[8 * kk + 2 * m], sh[8 * kk + 2 * m + 1]);
            unsigned B = cvtpk(sh[8 * kk + 4 + 2 * m], sh[8 * kk + 5 + 2 * m]);
            permswap(A, B);
            w[m] = A; w[2 + m] = B;
          }
          unsigned* pw = (unsigned*)&pa[2 * h2 + kk];
          pw[0] = w[0]; pw[1] = w[1]; pw[2] = w[2]; pw[3] = w[3];
        }
#pragma unroll
      for (int d0 = 0; d0 < 4; ++d0) {
        int vr = d0 * 32 + l31;
        int swz = (vr & 7) << 4;
#pragma unroll
        for (int ks = 0; ks < 4; ++ks) {
          short8 vf = *(const short8*)(VsB + cb + vr * 256 +
                                       (((half * 4 + ks) * 32 + hi * 16) ^ swz));
          o[d0] = __builtin_amdgcn_mfma_f32_32x32x16_bf16(pa[ks], vf,
                                                          o[d0], 0, 0, 0);
        }
      }
    }
    __syncthreads();
    cur ^= 1;
  }

  float lt;
  {
    unsigned la = __float_as_uint(lrun), lb = la;
    permswap(la, lb);
    lt = __uint_as_float(la) + __uint_as_float(lb);
  }
  float rinv = 1.f / lt;
#pragma unroll
  for (int reg = 0; reg < 16; ++reg) {
    int crow = (reg & 3) + 8 * (reg >> 2) + 4 * hi;
    float rb = __shfl(rinv, crow);
    size_t trow = (size_t)(q0 + crow) * HDIM + head * 128;
#pragma unroll
    for (int d0 = 0; d0 < 4; ++d0)
      Oattn[trow + d0 * 32 + l31] = f2bf(o[d0][reg] * rb);
  }
#undef STAGE
}

}  // namespace

extern "C" void kernel_launch(void* const* d_in, const int* in_sizes, int n_in,
                              void* d_out, int out_size, void* d_ws, size_t ws_size,
                              hipStream_t stream) {
  (void)in_sizes; (void)n_in; (void)out_size;
  const float* hs  = (const float*)d_in[0];
  const int*   pos = (const int*)d_in[2];
  const float* Wq  = (const float*)d_in[3];
  const float* Wk  = (const float*)d_in[4];
  const float* Wv  = (const float*)d_in[5];
  const float* Wo  = (const float*)d_in[6];

  float* out_res  = (float*)d_out;
  float* out_keys = out_res + (size_t)T_SEQ * HDIM;
  float* out_vals = out_keys + (size_t)NHEADS * T_SEQ * HEADD;

  const size_t NEL = (size_t)T_SEQ * HDIM;   // 16.7M elems = 32 MiB bf16
  dim3 b256(256);
  dim3 b512(512);
  dim3 gemmgrid(256);

  const bool big = ws_size >= (8 * NEL * 2 + (size_t)(2 << 20));

  if (big) {
    u16* Xb  = (u16*)d_ws;
    u16* Wt4 = Xb + NEL;
    u16* qb  = Wt4 + 4 * NEL;
    u16* kb  = qb + NEL;
    u16* vt  = kb + NEL;
    float* ropetab = (float*)(vt + NEL);

    const int nconv = (int)(NEL / 4 / 256);             // 16384
    k_prep<<<dim3(nconv + T_SEQ * 64 / 256), b256, 0, stream>>>(
        (const float4*)hs, (u16x4*)Xb, nconv, (int)(NEL / 4), pos, ropetab);
    k_transpose_all<<<dim3(HDIM / 64, HDIM / 64, 4), b256, 0, stream>>>(
        Wq, Wk, Wv, Wo, Wt4);

    k_gemm256<4><<<gemmgrid, b512, 0, stream>>>(Xb, Wt4, qb, nullptr, ropetab);
    k_gemm256<3><<<gemmgrid, b512, 0, stream>>>(Xb, Wt4 + NEL, kb, out_keys,
                                                ropetab);
    k_gemm256<2><<<gemmgrid, b512, 0, stream>>>(Xb, Wt4 + 2 * NEL, vt, out_vals,
                                                nullptr);
    k_flash3<<<dim3(NHEADS * (T_SEQ / 256)), b512, 0, stream>>>(qb, kb, vt, Xb);
    k_gemm256<1><<<gemmgrid, b512, 0, stream>>>(Xb, Wt4 + 3 * NEL, d_out,
                                                nullptr, nullptr);
  } else {
    u16* Xb = (u16*)d_ws;
    u16* Wt = Xb + NEL;
    u16* qb = Wt + NEL;
    u16* kb = qb + NEL;
    u16* vt = kb + NEL;
    float* ropetab = (float*)vt;
    dim3 tw(HDIM / 64, HDIM / 64);

    k_f32_to_bf16<<<dim3((int)(NEL / 4 / 256)), b256, 0, stream>>>(
        (const float4*)hs, (u16x4*)Xb, (int)(NEL / 4));
    k_rope_table<<<dim3(T_SEQ * 64 / 256), b256, 0, stream>>>(pos, ropetab);

    k_transpose_w<<<tw, b256, 0, stream>>>(Wq, Wt);
    k_gemm256<4><<<gemmgrid, b512, 0, stream>>>(Xb, Wt, qb, nullptr, ropetab);
    k_transpose_w<<<tw, b256, 0, stream>>>(Wk, Wt);
    k_gemm256<3><<<gemmgrid, b512, 0, stream>>>(Xb, Wt, kb, out_keys, ropetab);

    k_transpose_w<<<tw, b256, 0, stream>>>(Wv, Wt);
    k_gemm256<2><<<gemmgrid, b512, 0, stream>>>(Xb, Wt, vt, out_vals, nullptr);

    k_flash3<<<dim3(NHEADS * (T_SEQ / 256)), b512, 0, stream>>>(qb, kb, vt, Xb);

    k_transpose_w<<<tw, b256, 0, stream>>>(Wo, Wt);
    k_gemm256<1><<<gemmgrid, b512, 0, stream>>>(Xb, Wt, d_out, nullptr, nullptr);
  }
}